// Round 1
// baseline (670.896 us; speedup 1.0000x reference)
//
#include <hip/hip_runtime.h>
#include <hip/hip_bf16.h>

typedef unsigned short u16;
typedef __bf16 bf16x8 __attribute__((ext_vector_type(8)));
typedef float f32x4 __attribute__((ext_vector_type(4)));

#define H_DIM 2048
#define I_DIM 1408
#define T_TOK 1024
#define NEXP 8
#define LS 40  // LDS row stride in u16: 32 payload + 8 pad -> 80B rows, 16B-aligned, even 2-way bank pattern

__device__ __forceinline__ u16 f2bf(float f) {
    union { float f; unsigned u; } v; v.f = f;
    unsigned r = v.u + 0x7FFFu + ((v.u >> 16) & 1u);  // RNE
    return (u16)(r >> 16);
}
__device__ __forceinline__ unsigned pack2(float a, float b) {
    return (unsigned)f2bf(a) | ((unsigned)f2bf(b) << 16);
}

// ---------------- router: logits = x @ gw^T, top-2 + softmax, bucket per expert ----------------
__global__ __launch_bounds__(256)
void router_kernel(const float* __restrict__ x, const float* __restrict__ gw,
                   int* __restrict__ counts, int* __restrict__ tok, float* __restrict__ tw) {
    int wave = threadIdx.x >> 6;
    int lane = threadIdx.x & 63;
    int t = blockIdx.x * 4 + wave;
    const float* xr = x + (size_t)t * H_DIM;
    float acc[NEXP];
#pragma unroll
    for (int e = 0; e < NEXP; e++) acc[e] = 0.f;
    for (int h = lane; h < H_DIM; h += 64) {
        float xv = xr[h];
#pragma unroll
        for (int e = 0; e < NEXP; e++) acc[e] += xv * gw[e * H_DIM + h];
    }
#pragma unroll
    for (int e = 0; e < NEXP; e++) {
#pragma unroll
        for (int off = 32; off > 0; off >>= 1) acc[e] += __shfl_xor(acc[e], off);
    }
    if (lane == 0) {
        int i0 = 0; float v0 = acc[0];
#pragma unroll
        for (int e = 1; e < NEXP; e++) if (acc[e] > v0) { v0 = acc[e]; i0 = e; }  // ties -> lowest idx, matches top_k
        int i1 = -1; float v1 = -3.0e38f;
#pragma unroll
        for (int e = 0; e < NEXP; e++) if (e != i0 && acc[e] > v1) { v1 = acc[e]; i1 = e; }
        float ex = __expf(v1 - v0);          // v1 <= v0, no overflow
        float w0 = 1.f / (1.f + ex);
        float w1 = 1.f - w0;
        int s0 = atomicAdd(&counts[i0], 1);
        tok[i0 * T_TOK + s0] = t; tw[i0 * T_TOK + s0] = w0;
        int s1 = atomicAdd(&counts[i1], 1);
        tok[i1 * T_TOK + s1] = t; tw[i1 * T_TOK + s1] = w1;
    }
}

// ---------------- fused gate+up GEMM: h = silu(x@Wg^T) * (x@Wu^T) * wt  (bf16 out) ----------------
// tile 128(M) x 128(N) x 32(K), 4 waves in 2x2, each wave 64x64 per matrix.
template<bool ROUTED>
__global__ __launch_bounds__(256, 2)
void gate_up_kernel(const float* __restrict__ x,
                    const float* __restrict__ Wg_all, const float* __restrict__ Wu_all,
                    const int* __restrict__ counts, const int* __restrict__ tok,
                    const float* __restrict__ tw, u16* __restrict__ hout) {
    __shared__ u16 lA[128 * LS];
    __shared__ u16 lG[128 * LS];
    __shared__ u16 lU[128 * LS];

    int e = blockIdx.z;
    int cnt = T_TOK, hbase = 0;
    if (ROUTED) {
        cnt = counts[e];
        int p = 0;
        for (int i = 0; i < NEXP; i++) { int c = counts[i]; if (i < e) p += c; }
        hbase = p;  // compact prefix offset into h buffer
    }
    int m0 = blockIdx.y * 128;
    if (m0 >= cnt) return;
    int n0 = blockIdx.x * 128;
    const float* Wg = Wg_all + (ROUTED ? (size_t)e * I_DIM * H_DIM : 0);
    const float* Wu = Wu_all + (ROUTED ? (size_t)e * I_DIM * H_DIM : 0);

    int tid = threadIdx.x;
    int lane = tid & 63;
    int w = tid >> 6;
    int wm = w & 1, wn = w >> 1;

    // staging: 128x32 fp32 per matrix = 1024 float4 slots; 4 slots/thread
    const float* ap[4]; const float* gp[4]; const float* up[4];
    int sidx[4];
#pragma unroll
    for (int i = 0; i < 4; i++) {
        int slot = tid + i * 256;
        int row = slot >> 3, c4 = slot & 7;
        sidx[i] = row * LS + c4 * 4;
        int trow = m0 + row; if (trow > cnt - 1) trow = cnt - 1;   // clamp padding rows
        int tix = ROUTED ? tok[e * T_TOK + trow] : trow;
        ap[i] = x + (size_t)tix * H_DIM + c4 * 4;
        gp[i] = Wg + (size_t)(n0 + row) * H_DIM + c4 * 4;
        up[i] = Wu + (size_t)(n0 + row) * H_DIM + c4 * 4;
    }

    f32x4 zero = {0.f, 0.f, 0.f, 0.f};
    f32x4 accg[4][4], accu[4][4];
#pragma unroll
    for (int a = 0; a < 4; a++)
#pragma unroll
        for (int b = 0; b < 4; b++) { accg[a][b] = zero; accu[a][b] = zero; }

    int r16 = lane & 15, kq = lane >> 4;

    for (int k0 = 0; k0 < H_DIM; k0 += 32) {
#pragma unroll
        for (int i = 0; i < 4; i++) {
            float4 av = *(const float4*)(ap[i] + k0);
            float4 gv = *(const float4*)(gp[i] + k0);
            float4 uv = *(const float4*)(up[i] + k0);
            uint2 pa; pa.x = pack2(av.x, av.y); pa.y = pack2(av.z, av.w);
            uint2 pg; pg.x = pack2(gv.x, gv.y); pg.y = pack2(gv.z, gv.w);
            uint2 pu; pu.x = pack2(uv.x, uv.y); pu.y = pack2(uv.z, uv.w);
            *(uint2*)&lA[sidx[i]] = pa;
            *(uint2*)&lG[sidx[i]] = pg;
            *(uint2*)&lU[sidx[i]] = pu;
        }
        __syncthreads();
        bf16x8 af[4], gf[4], uf[4];
#pragma unroll
        for (int mi = 0; mi < 4; mi++)
            af[mi] = *(const bf16x8*)&lA[(wm * 64 + mi * 16 + r16) * LS + kq * 8];
#pragma unroll
        for (int ni = 0; ni < 4; ni++) {
            gf[ni] = *(const bf16x8*)&lG[(wn * 64 + ni * 16 + r16) * LS + kq * 8];
            uf[ni] = *(const bf16x8*)&lU[(wn * 64 + ni * 16 + r16) * LS + kq * 8];
        }
#pragma unroll
        for (int mi = 0; mi < 4; mi++)
#pragma unroll
            for (int ni = 0; ni < 4; ni++) {
                accg[mi][ni] = __builtin_amdgcn_mfma_f32_16x16x32_bf16(af[mi], gf[ni], accg[mi][ni], 0, 0, 0);
                accu[mi][ni] = __builtin_amdgcn_mfma_f32_16x16x32_bf16(af[mi], uf[ni], accu[mi][ni], 0, 0, 0);
            }
        __syncthreads();
    }

    // epilogue: C/D mapping col=lane&15, row=(lane>>4)*4+reg (m89-verified)
#pragma unroll
    for (int mi = 0; mi < 4; mi++) {
#pragma unroll
        for (int r = 0; r < 4; r++) {
            int row = wm * 64 + mi * 16 + kq * 4 + r;
            int gr = m0 + row;
            if (gr < cnt) {
                float wt = ROUTED ? tw[e * T_TOK + gr] : 1.0f;
                u16* hrow = hout + (size_t)(hbase + gr) * I_DIM + n0;
#pragma unroll
                for (int ni = 0; ni < 4; ni++) {
                    float g = accg[mi][ni][r], u = accu[mi][ni][r];
                    float hv = (g / (1.f + __expf(-g))) * u * wt;
                    hrow[wn * 64 + ni * 16 + r16] = f2bf(hv);
                }
            }
        }
    }
}

// ---------------- down GEMM: y = h @ Wd^T; shared: store, routed: atomicAdd scatter ----------------
template<bool ROUTED>
__global__ __launch_bounds__(256, 2)
void down_kernel(const u16* __restrict__ hin, const float* __restrict__ Wd_all,
                 const int* __restrict__ counts, const int* __restrict__ tok,
                 float* __restrict__ out) {
    __shared__ u16 lA[128 * LS];
    __shared__ u16 lB[128 * LS];

    int e = blockIdx.z;
    int cnt = T_TOK, hbase = 0;
    if (ROUTED) {
        cnt = counts[e];
        int p = 0;
        for (int i = 0; i < NEXP; i++) { int c = counts[i]; if (i < e) p += c; }
        hbase = p;
    }
    int m0 = blockIdx.y * 128;
    if (m0 >= cnt) return;
    int n0 = blockIdx.x * 128;
    const float* Wd = Wd_all + (ROUTED ? (size_t)e * H_DIM * I_DIM : 0);

    int tid = threadIdx.x;
    int lane = tid & 63;
    int w = tid >> 6;
    int wm = w & 1, wn = w >> 1;

    // A (bf16 h): 128x32 u16 = 512 x 16B slots; 2 slots/thread
    const u16* ap[2]; int a_idx[2];
#pragma unroll
    for (int i = 0; i < 2; i++) {
        int slot = tid + i * 256;
        int row = slot >> 2, c8 = slot & 3;
        int hr = m0 + row; if (hr > cnt - 1) hr = cnt - 1;
        ap[i] = hin + (size_t)(hbase + hr) * I_DIM + c8 * 8;
        a_idx[i] = row * LS + c8 * 8;
    }
    // B (fp32 Wd): 128x32 fp32 = 1024 float4 slots; 4 slots/thread
    const float* bp[4]; int b_idx[4];
#pragma unroll
    for (int i = 0; i < 4; i++) {
        int slot = tid + i * 256;
        int row = slot >> 3, c4 = slot & 7;
        bp[i] = Wd + (size_t)(n0 + row) * I_DIM + c4 * 4;
        b_idx[i] = row * LS + c4 * 4;
    }

    f32x4 zero = {0.f, 0.f, 0.f, 0.f};
    f32x4 acc[4][4];
#pragma unroll
    for (int a = 0; a < 4; a++)
#pragma unroll
        for (int b = 0; b < 4; b++) acc[a][b] = zero;

    int r16 = lane & 15, kq = lane >> 4;

    for (int k0 = 0; k0 < I_DIM; k0 += 32) {  // 1408 = 44 * 32, exact
#pragma unroll
        for (int i = 0; i < 2; i++) {
            uint4 v = *(const uint4*)(ap[i] + k0);
            *(uint4*)&lA[a_idx[i]] = v;
        }
#pragma unroll
        for (int i = 0; i < 4; i++) {
            float4 bv = *(const float4*)(bp[i] + k0);
            uint2 pb; pb.x = pack2(bv.x, bv.y); pb.y = pack2(bv.z, bv.w);
            *(uint2*)&lB[b_idx[i]] = pb;
        }
        __syncthreads();
        bf16x8 af[4], bfr[4];
#pragma unroll
        for (int mi = 0; mi < 4; mi++)
            af[mi] = *(const bf16x8*)&lA[(wm * 64 + mi * 16 + r16) * LS + kq * 8];
#pragma unroll
        for (int ni = 0; ni < 4; ni++)
            bfr[ni] = *(const bf16x8*)&lB[(wn * 64 + ni * 16 + r16) * LS + kq * 8];
#pragma unroll
        for (int mi = 0; mi < 4; mi++)
#pragma unroll
            for (int ni = 0; ni < 4; ni++)
                acc[mi][ni] = __builtin_amdgcn_mfma_f32_16x16x32_bf16(af[mi], bfr[ni], acc[mi][ni], 0, 0, 0);
        __syncthreads();
    }

#pragma unroll
    for (int mi = 0; mi < 4; mi++) {
#pragma unroll
        for (int r = 0; r < 4; r++) {
            int row = wm * 64 + mi * 16 + kq * 4 + r;
            int gr = m0 + row;
            if (gr < cnt) {
                float* orow;
                if (ROUTED) {
                    int t = tok[e * T_TOK + gr];
                    orow = out + (size_t)t * H_DIM + n0;
                } else {
                    orow = out + (size_t)gr * H_DIM + n0;
                }
#pragma unroll
                for (int ni = 0; ni < 4; ni++) {
                    float yv = acc[mi][ni][r];
                    int col = wn * 64 + ni * 16 + r16;
                    if (ROUTED) atomicAdd(&orow[col], yv);
                    else        orow[col] = yv;
                }
            }
        }
    }
}

extern "C" void kernel_launch(void* const* d_in, const int* in_sizes, int n_in,
                              void* d_out, int out_size, void* d_ws, size_t ws_size,
                              hipStream_t stream) {
    const float* x   = (const float*)d_in[0];  // [1,1024,2048]
    const float* gw  = (const float*)d_in[1];  // [8,2048]
    const float* egw = (const float*)d_in[2];  // [8,1408,2048]
    const float* euw = (const float*)d_in[3];  // [8,1408,2048]
    const float* edw = (const float*)d_in[4];  // [8,2048,1408]
    const float* sgw = (const float*)d_in[5];  // [1408,2048]
    const float* suw = (const float*)d_in[6];  // [1408,2048]
    const float* sdw = (const float*)d_in[7];  // [2048,1408]
    float* out = (float*)d_out;                // [1,1024,2048] fp32

    // workspace layout (~8.8 MB): counts | tok | tw | h_routed(2048x1408 bf16) | h_shared(1024x1408 bf16)
    char* ws = (char*)d_ws;
    int*   counts = (int*)ws;                        // 32 B (memset below)
    int*   tok    = (int*)(ws + 256);                // 8*1024 int
    float* tw     = (float*)(ws + 256 + 32768);      // 8*1024 float
    u16*   h_r    = (u16*)(ws + 65792);              // 16B-aligned
    u16*   h_s    = h_r + (size_t)2048 * I_DIM;

    hipMemsetAsync(counts, 0, 32, stream);
    router_kernel<<<256, 256, 0, stream>>>(x, gw, counts, tok, tw);
    // shared expert h
    gate_up_kernel<false><<<dim3(11, 8, 1), 256, 0, stream>>>(x, sgw, suw, nullptr, nullptr, nullptr, h_s);
    // routed experts h (grid.y = worst-case M tiles; blocks early-exit past counts[e])
    gate_up_kernel<true><<<dim3(11, 8, 8), 256, 0, stream>>>(x, egw, euw, counts, tok, tw, h_r);
    // shared down writes every out element (no zero-init needed), then routed down atomically adds
    down_kernel<false><<<dim3(16, 8, 1), 256, 0, stream>>>(h_s, sdw, nullptr, nullptr, out);
    down_kernel<true><<<dim3(16, 8, 8), 256, 0, stream>>>(h_r, edw, counts, tok, out);
}

// Round 2
// 543.159 us; speedup vs baseline: 1.2352x; 1.2352x over previous
//
#include <hip/hip_runtime.h>
#include <hip/hip_bf16.h>

typedef unsigned short u16;
typedef __bf16 bf16x8 __attribute__((ext_vector_type(8)));
typedef float f32x4 __attribute__((ext_vector_type(4)));

#define H_DIM 2048
#define I_DIM 1408
#define T_TOK 1024
#define NEXP 8
#define LS 40  // LDS row stride in u16: 32 payload + 8 pad -> 80B rows, 16B-aligned

__device__ __forceinline__ u16 f2bf(float f) {
    union { float f; unsigned u; } v; v.f = f;
    unsigned r = v.u + 0x7FFFu + ((v.u >> 16) & 1u);  // RNE
    return (u16)(r >> 16);
}
// HW packed convert: v_cvt_pk_bf16_f32
__device__ __forceinline__ unsigned pack2(float a, float b) {
    float2 t; t.x = a; t.y = b;
    __hip_bfloat162 h = __float22bfloat162_rn(t);
    union { __hip_bfloat162 h; unsigned u; } v; v.h = h;
    return v.u;
}
__device__ __forceinline__ uint2 pack4(float4 f) {
    uint2 r; r.x = pack2(f.x, f.y); r.y = pack2(f.z, f.w); return r;
}

// ---------------- router ----------------
__global__ __launch_bounds__(256)
void router_kernel(const float* __restrict__ x, const float* __restrict__ gw,
                   int* __restrict__ counts, int* __restrict__ tok, float* __restrict__ tw) {
    int wave = threadIdx.x >> 6;
    int lane = threadIdx.x & 63;
    int t = blockIdx.x * 4 + wave;
    const float* xr = x + (size_t)t * H_DIM;
    float acc[NEXP];
#pragma unroll
    for (int e = 0; e < NEXP; e++) acc[e] = 0.f;
    for (int h = lane; h < H_DIM; h += 64) {
        float xv = xr[h];
#pragma unroll
        for (int e = 0; e < NEXP; e++) acc[e] += xv * gw[e * H_DIM + h];
    }
#pragma unroll
    for (int e = 0; e < NEXP; e++) {
#pragma unroll
        for (int off = 32; off > 0; off >>= 1) acc[e] += __shfl_xor(acc[e], off);
    }
    if (lane == 0) {
        int i0 = 0; float v0 = acc[0];
#pragma unroll
        for (int e = 1; e < NEXP; e++) if (acc[e] > v0) { v0 = acc[e]; i0 = e; }
        int i1 = -1; float v1 = -3.0e38f;
#pragma unroll
        for (int e = 0; e < NEXP; e++) if (e != i0 && acc[e] > v1) { v1 = acc[e]; i1 = e; }
        float ex = __expf(v1 - v0);
        float w0 = 1.f / (1.f + ex);
        float w1 = 1.f - w0;
        int s0 = atomicAdd(&counts[i0], 1);
        tok[i0 * T_TOK + s0] = t; tw[i0 * T_TOK + s0] = w0;
        int s1 = atomicAdd(&counts[i1], 1);
        tok[i1 * T_TOK + s1] = t; tw[i1 * T_TOK + s1] = w1;
    }
}

// ---------------- fused gate+up GEMM (combined routed z<8 / shared z==8) ----------------
// tile 64(M) x 128(N) x 32(K); 4 waves side-by-side over N, each wave 64x32.
__global__ __launch_bounds__(256, 2)
void gate_up_kernel(const float* __restrict__ x,
                    const float* __restrict__ egw, const float* __restrict__ euw,
                    const float* __restrict__ sgw, const float* __restrict__ suw,
                    const int* __restrict__ counts, const int* __restrict__ tok,
                    const float* __restrict__ tw,
                    u16* __restrict__ h_r, u16* __restrict__ h_s) {
    __shared__ u16 lA[64 * LS];
    __shared__ u16 lG[128 * LS];
    __shared__ u16 lU[128 * LS];

    int e = blockIdx.z;
    bool routed = (e < NEXP);
    int cnt, hbase;
    const float *Wg, *Wu; u16* hout;
    if (routed) {
        cnt = counts[e];
        int p = 0;
#pragma unroll
        for (int i = 0; i < NEXP; i++) { int c = counts[i]; if (i < e) p += c; }
        hbase = p;
        Wg = egw + (size_t)e * I_DIM * H_DIM;
        Wu = euw + (size_t)e * I_DIM * H_DIM;
        hout = h_r;
    } else {
        cnt = T_TOK; hbase = 0; Wg = sgw; Wu = suw; hout = h_s;
    }
    int m0 = blockIdx.y * 64;
    if (m0 >= cnt) return;
    int n0 = blockIdx.x * 128;

    int tid = threadIdx.x;
    int lane = tid & 63;
    int w = tid >> 6;  // wave id 0..3 -> N sub-tile

    // A staging: 64x32 fp32 = 512 float4 slots, 2/thread
    const float* ap[2]; int sa[2];
#pragma unroll
    for (int i = 0; i < 2; i++) {
        int slot = tid + i * 256;
        int row = slot >> 3, c4 = slot & 7;
        sa[i] = row * LS + c4 * 4;
        int trow = m0 + row; if (trow > cnt - 1) trow = cnt - 1;
        int tix = routed ? tok[e * T_TOK + trow] : trow;
        ap[i] = x + (size_t)tix * H_DIM + c4 * 4;
    }
    // G/U staging: 128x32 fp32 = 1024 float4 slots, 4/thread
    const float* gp[4]; const float* up[4]; int sg[4];
#pragma unroll
    for (int i = 0; i < 4; i++) {
        int slot = tid + i * 256;
        int row = slot >> 3, c4 = slot & 7;
        sg[i] = row * LS + c4 * 4;
        gp[i] = Wg + (size_t)(n0 + row) * H_DIM + c4 * 4;
        up[i] = Wu + (size_t)(n0 + row) * H_DIM + c4 * 4;
    }

    f32x4 zero = {0.f, 0.f, 0.f, 0.f};
    f32x4 accg[4][2], accu[4][2];
#pragma unroll
    for (int a = 0; a < 4; a++)
#pragma unroll
        for (int b = 0; b < 2; b++) { accg[a][b] = zero; accu[a][b] = zero; }

    int r16 = lane & 15, kq = lane >> 4;

    // prologue loads
    float4 ra[2], rg[4], ru[4];
#pragma unroll
    for (int i = 0; i < 2; i++) ra[i] = *(const float4*)(ap[i]);
#pragma unroll
    for (int i = 0; i < 4; i++) { rg[i] = *(const float4*)(gp[i]); ru[i] = *(const float4*)(up[i]); }

    for (int k0 = 0; k0 < H_DIM; k0 += 32) {
#pragma unroll
        for (int i = 0; i < 2; i++) *(uint2*)&lA[sa[i]] = pack4(ra[i]);
#pragma unroll
        for (int i = 0; i < 4; i++) {
            *(uint2*)&lG[sg[i]] = pack4(rg[i]);
            *(uint2*)&lU[sg[i]] = pack4(ru[i]);
        }
        __syncthreads();
        if (k0 + 32 < H_DIM) {  // prefetch next K-slice; in flight across MFMA section
            int kn = k0 + 32;
#pragma unroll
            for (int i = 0; i < 2; i++) ra[i] = *(const float4*)(ap[i] + kn);
#pragma unroll
            for (int i = 0; i < 4; i++) { rg[i] = *(const float4*)(gp[i] + kn); ru[i] = *(const float4*)(up[i] + kn); }
        }
        bf16x8 af[4], gf[2], uf[2];
#pragma unroll
        for (int mi = 0; mi < 4; mi++)
            af[mi] = *(const bf16x8*)&lA[(mi * 16 + r16) * LS + kq * 8];
#pragma unroll
        for (int ni = 0; ni < 2; ni++) {
            gf[ni] = *(const bf16x8*)&lG[(w * 32 + ni * 16 + r16) * LS + kq * 8];
            uf[ni] = *(const bf16x8*)&lU[(w * 32 + ni * 16 + r16) * LS + kq * 8];
        }
#pragma unroll
        for (int mi = 0; mi < 4; mi++)
#pragma unroll
            for (int ni = 0; ni < 2; ni++) {
                accg[mi][ni] = __builtin_amdgcn_mfma_f32_16x16x32_bf16(af[mi], gf[ni], accg[mi][ni], 0, 0, 0);
                accu[mi][ni] = __builtin_amdgcn_mfma_f32_16x16x32_bf16(af[mi], uf[ni], accu[mi][ni], 0, 0, 0);
            }
        __syncthreads();
    }

    // epilogue: C/D mapping col=lane&15, row=(lane>>4)*4+reg
#pragma unroll
    for (int mi = 0; mi < 4; mi++) {
#pragma unroll
        for (int r = 0; r < 4; r++) {
            int row = mi * 16 + kq * 4 + r;
            int gr = m0 + row;
            if (gr < cnt) {
                float wt = routed ? tw[e * T_TOK + gr] : 1.0f;
                u16* hrow = hout + (size_t)(hbase + gr) * I_DIM + n0 + w * 32;
#pragma unroll
                for (int ni = 0; ni < 2; ni++) {
                    float g = accg[mi][ni][r], u = accu[mi][ni][r];
                    float hv = (g / (1.f + __expf(-g))) * u * wt;
                    hrow[ni * 16 + r16] = f2bf(hv);
                }
            }
        }
    }
}

// ---------------- down GEMM (combined routed z<8 / shared z==8), atomicAdd into zeroed out ----------------
__global__ __launch_bounds__(256, 2)
void down_kernel(const u16* __restrict__ h_r, const u16* __restrict__ h_s,
                 const float* __restrict__ edw, const float* __restrict__ sdw,
                 const int* __restrict__ counts, const int* __restrict__ tok,
                 float* __restrict__ out) {
    __shared__ u16 lA[64 * LS];
    __shared__ u16 lB[128 * LS];

    int e = blockIdx.z;
    bool routed = (e < NEXP);
    int cnt, hbase;
    const float* Wd; const u16* hin;
    if (routed) {
        cnt = counts[e];
        int p = 0;
#pragma unroll
        for (int i = 0; i < NEXP; i++) { int c = counts[i]; if (i < e) p += c; }
        hbase = p;
        Wd = edw + (size_t)e * H_DIM * I_DIM;
        hin = h_r;
    } else {
        cnt = T_TOK; hbase = 0; Wd = sdw; hin = h_s;
    }
    int m0 = blockIdx.y * 64;
    if (m0 >= cnt) return;
    int n0 = blockIdx.x * 128;

    int tid = threadIdx.x;
    int lane = tid & 63;
    int w = tid >> 6;

    // A (bf16 h): 64x32 u16 = 256 x 16B slots, 1/thread
    int arow = tid >> 2, ac8 = tid & 3;
    int hr = m0 + arow; if (hr > cnt - 1) hr = cnt - 1;
    const u16* ap = hin + (size_t)(hbase + hr) * I_DIM + ac8 * 8;
    int sa = arow * LS + ac8 * 8;
    // B (fp32 Wd): 128x32 fp32 = 1024 float4 slots, 4/thread
    const float* bp[4]; int sb[4];
#pragma unroll
    for (int i = 0; i < 4; i++) {
        int slot = tid + i * 256;
        int row = slot >> 3, c4 = slot & 7;
        bp[i] = Wd + (size_t)(n0 + row) * I_DIM + c4 * 4;
        sb[i] = row * LS + c4 * 4;
    }

    f32x4 zero = {0.f, 0.f, 0.f, 0.f};
    f32x4 acc[4][2];
#pragma unroll
    for (int a = 0; a < 4; a++)
#pragma unroll
        for (int b = 0; b < 2; b++) acc[a][b] = zero;

    int r16 = lane & 15, kq = lane >> 4;

    uint4 ra = *(const uint4*)(ap);
    float4 rb[4];
#pragma unroll
    for (int i = 0; i < 4; i++) rb[i] = *(const float4*)(bp[i]);

    for (int k0 = 0; k0 < I_DIM; k0 += 32) {  // 1408 = 44*32
        *(uint4*)&lA[sa] = ra;
#pragma unroll
        for (int i = 0; i < 4; i++) *(uint2*)&lB[sb[i]] = pack4(rb[i]);
        __syncthreads();
        if (k0 + 32 < I_DIM) {
            int kn = k0 + 32;
            ra = *(const uint4*)(ap + kn);
#pragma unroll
            for (int i = 0; i < 4; i++) rb[i] = *(const float4*)(bp[i] + kn);
        }
        bf16x8 af[4], bfr[2];
#pragma unroll
        for (int mi = 0; mi < 4; mi++)
            af[mi] = *(const bf16x8*)&lA[(mi * 16 + r16) * LS + kq * 8];
#pragma unroll
        for (int ni = 0; ni < 2; ni++)
            bfr[ni] = *(const bf16x8*)&lB[(w * 32 + ni * 16 + r16) * LS + kq * 8];
#pragma unroll
        for (int mi = 0; mi < 4; mi++)
#pragma unroll
            for (int ni = 0; ni < 2; ni++)
                acc[mi][ni] = __builtin_amdgcn_mfma_f32_16x16x32_bf16(af[mi], bfr[ni], acc[mi][ni], 0, 0, 0);
        __syncthreads();
    }

#pragma unroll
    for (int mi = 0; mi < 4; mi++) {
#pragma unroll
        for (int r = 0; r < 4; r++) {
            int row = mi * 16 + kq * 4 + r;
            int gr = m0 + row;
            if (gr < cnt) {
                int t = routed ? tok[e * T_TOK + gr] : gr;
                float* orow = out + (size_t)t * H_DIM + n0 + w * 32;
#pragma unroll
                for (int ni = 0; ni < 2; ni++)
                    atomicAdd(&orow[ni * 16 + r16], acc[mi][ni][r]);
            }
        }
    }
}

extern "C" void kernel_launch(void* const* d_in, const int* in_sizes, int n_in,
                              void* d_out, int out_size, void* d_ws, size_t ws_size,
                              hipStream_t stream) {
    const float* x   = (const float*)d_in[0];
    const float* gw  = (const float*)d_in[1];
    const float* egw = (const float*)d_in[2];
    const float* euw = (const float*)d_in[3];
    const float* edw = (const float*)d_in[4];
    const float* sgw = (const float*)d_in[5];
    const float* suw = (const float*)d_in[6];
    const float* sdw = (const float*)d_in[7];
    float* out = (float*)d_out;

    char* ws = (char*)d_ws;
    int*   counts = (int*)ws;
    int*   tok    = (int*)(ws + 256);
    float* tw     = (float*)(ws + 256 + 32768);
    u16*   h_r    = (u16*)(ws + 65792);
    u16*   h_s    = h_r + (size_t)2048 * I_DIM;

    hipMemsetAsync(counts, 0, 32, stream);
    hipMemsetAsync(out, 0, (size_t)T_TOK * H_DIM * sizeof(float), stream);
    router_kernel<<<256, 256, 0, stream>>>(x, gw, counts, tok, tw);
    // combined gate+up: z 0..7 routed experts, z==8 shared (cnt=1024)
    gate_up_kernel<<<dim3(11, 16, 9), 256, 0, stream>>>(x, egw, euw, sgw, suw, counts, tok, tw, h_r, h_s);
    // combined down: atomicAdd into zeroed out
    down_kernel<<<dim3(16, 16, 9), 256, 0, stream>>>(h_r, h_s, edw, sdw, counts, tok, out);
}

// Round 3
// 523.700 us; speedup vs baseline: 1.2811x; 1.0372x over previous
//
#include <hip/hip_runtime.h>
#include <hip/hip_bf16.h>

typedef unsigned short u16;
typedef __bf16 bf16x8 __attribute__((ext_vector_type(8)));
typedef float f32x4 __attribute__((ext_vector_type(4)));

#define H_DIM 2048
#define I_DIM 1408
#define T_TOK 1024
#define NEXP 8
#define LS 40  // fallback-path LDS stride

__device__ __forceinline__ u16 f2bf(float f) {
    union { float f; unsigned u; } v; v.f = f;
    unsigned r = v.u + 0x7FFFu + ((v.u >> 16) & 1u);  // RNE
    return (u16)(r >> 16);
}
__device__ __forceinline__ unsigned pack2(float a, float b) {
    float2 t; t.x = a; t.y = b;
    __hip_bfloat162 h = __float22bfloat162_rn(t);  // v_cvt_pk_bf16_f32
    union { __hip_bfloat162 h; unsigned u; } v; v.h = h;
    return v.u;
}
__device__ __forceinline__ uint2 pack4(float4 f) {
    uint2 r; r.x = pack2(f.x, f.y); r.y = pack2(f.z, f.w); return r;
}
// async global->LDS, 16B per lane; lds must be wave-uniform
__device__ __forceinline__ void g2l16(const void* g, void* l) {
    __builtin_amdgcn_global_load_lds((const __attribute__((address_space(1))) void*)g,
                                     (__attribute__((address_space(3))) void*)l, 16, 0, 0);
}

// ---------------- router ----------------
__global__ __launch_bounds__(256)
void router_kernel(const float* __restrict__ x, const float* __restrict__ gw,
                   int* __restrict__ counts, int* __restrict__ tok, float* __restrict__ tw) {
    int wave = threadIdx.x >> 6;
    int lane = threadIdx.x & 63;
    int t = blockIdx.x * 4 + wave;
    const float* xr = x + (size_t)t * H_DIM;
    float acc[NEXP];
#pragma unroll
    for (int e = 0; e < NEXP; e++) acc[e] = 0.f;
    for (int h = lane; h < H_DIM; h += 64) {
        float xv = xr[h];
#pragma unroll
        for (int e = 0; e < NEXP; e++) acc[e] += xv * gw[e * H_DIM + h];
    }
#pragma unroll
    for (int e = 0; e < NEXP; e++) {
#pragma unroll
        for (int off = 32; off > 0; off >>= 1) acc[e] += __shfl_xor(acc[e], off);
    }
    if (lane == 0) {
        int i0 = 0; float v0 = acc[0];
#pragma unroll
        for (int e = 1; e < NEXP; e++) if (acc[e] > v0) { v0 = acc[e]; i0 = e; }
        int i1 = -1; float v1 = -3.0e38f;
#pragma unroll
        for (int e = 0; e < NEXP; e++) if (e != i0 && acc[e] > v1) { v1 = acc[e]; i1 = e; }
        float ex = __expf(v1 - v0);
        float w0 = 1.f / (1.f + ex);
        float w1 = 1.f - w0;
        int s0 = atomicAdd(&counts[i0], 1);
        tok[i0 * T_TOK + s0] = t; tw[i0 * T_TOK + s0] = w0;
        int s1 = atomicAdd(&counts[i1], 1);
        tok[i1 * T_TOK + s1] = t; tw[i1 * T_TOK + s1] = w1;
    }
}

// ---------------- fp32 -> bf16 pre-convert (7 regions via blockIdx.z) ----------------
struct Cvt7 { const float* in[7]; u16* out[7]; int nchunk[7]; };
__global__ __launch_bounds__(256)
void convert_bf(Cvt7 a) {
    int z = blockIdx.z;
    int n = a.nchunk[z];
    const float* in = a.in[z]; u16* out = a.out[z];
    for (int i = blockIdx.x * 256 + threadIdx.x; i < n; i += gridDim.x * 256) {
        const float4* p = (const float4*)(in + (size_t)i * 8);
        float4 f0 = p[0], f1 = p[1];
        uint4 o; o.x = pack2(f0.x, f0.y); o.y = pack2(f0.z, f0.w);
        o.z = pack2(f1.x, f1.y); o.w = pack2(f1.z, f1.w);
        *(uint4*)(out + (size_t)i * 8) = o;
    }
}

// ================= FAST PATH: bf16 GEMMs with global_load_lds =================
// gate_up: tile 64(M) x 128(N) x 64(K). 4 waves, each owns full M=64 and a 32-wide N slice.
// LDS layout: row-major 64/128 rows x 64 bf16 (8 chunks of 16B per row), chunk c holds
// global chunk c ^ (row&7) -> conflict-free ds_read_b128 fragment loads.
__global__ __launch_bounds__(256, 3)
void gate_up_bf(const u16* __restrict__ xb,
                const u16* __restrict__ egw, const u16* __restrict__ euw,
                const u16* __restrict__ sgw, const u16* __restrict__ suw,
                const int* __restrict__ counts, const int* __restrict__ tok,
                const float* __restrict__ tw,
                u16* __restrict__ h_r, u16* __restrict__ h_s) {
    __shared__ u16 lA[64 * 64];    // 8 KB
    __shared__ u16 lG[128 * 64];   // 16 KB
    __shared__ u16 lU[128 * 64];   // 16 KB

    int e = blockIdx.z;
    bool routed = (e < NEXP);
    int cnt, hbase; const u16 *Wg, *Wu; u16* hout;
    if (routed) {
        cnt = counts[e];
        int p = 0;
#pragma unroll
        for (int i = 0; i < NEXP; i++) { int c = counts[i]; if (i < e) p += c; }
        hbase = p;
        Wg = egw + (size_t)e * I_DIM * H_DIM;
        Wu = euw + (size_t)e * I_DIM * H_DIM;
        hout = h_r;
    } else { cnt = T_TOK; hbase = 0; Wg = sgw; Wu = suw; hout = h_s; }
    int m0 = blockIdx.y * 64;
    if (m0 >= cnt) return;
    int n0 = blockIdx.x * 128;

    int tid = threadIdx.x, lane = tid & 63, w = tid >> 6;

    // A staging: 512 chunks; wave w instr j<2 covers chunks [w*128+j*64, +64)
    const u16* aptr[2]; u16* alds[2];
#pragma unroll
    for (int j = 0; j < 2; j++) {
        int chunk = w * 128 + j * 64 + lane;
        int row = chunk >> 3, cl = chunk & 7;
        int cg = cl ^ (row & 7);
        int trow = m0 + row; if (trow > cnt - 1) trow = cnt - 1;
        int tix = routed ? tok[e * T_TOK + trow] : trow;
        aptr[j] = xb + (size_t)tix * H_DIM + cg * 8;
        alds[j] = &lA[(w * 128 + j * 64) * 8];
    }
    // G/U staging: 1024 chunks each; wave w instr j<4 covers [w*256+j*64, +64)
    const u16* gptr[4]; const u16* uptr[4]; u16* glds[4]; u16* ulds[4];
#pragma unroll
    for (int j = 0; j < 4; j++) {
        int chunk = w * 256 + j * 64 + lane;
        int row = chunk >> 3, cl = chunk & 7;
        int cg = cl ^ (row & 7);
        gptr[j] = Wg + (size_t)(n0 + row) * H_DIM + cg * 8;
        uptr[j] = Wu + (size_t)(n0 + row) * H_DIM + cg * 8;
        glds[j] = &lG[(w * 256 + j * 64) * 8];
        ulds[j] = &lU[(w * 256 + j * 64) * 8];
    }

    f32x4 zero = {0.f, 0.f, 0.f, 0.f};
    f32x4 accg[4][2], accu[4][2];
#pragma unroll
    for (int a = 0; a < 4; a++)
#pragma unroll
        for (int b = 0; b < 2; b++) { accg[a][b] = zero; accu[a][b] = zero; }

    int r16 = lane & 15, q = lane >> 4;

    for (int k0 = 0; k0 < H_DIM; k0 += 64) {
#pragma unroll
        for (int j = 0; j < 2; j++) g2l16(aptr[j] + k0, alds[j]);
#pragma unroll
        for (int j = 0; j < 4; j++) { g2l16(gptr[j] + k0, glds[j]); g2l16(uptr[j] + k0, ulds[j]); }
        __syncthreads();
#pragma unroll
        for (int kh = 0; kh < 2; kh++) {
            bf16x8 af[4], gf[2], uf[2];
#pragma unroll
            for (int mi = 0; mi < 4; mi++) {
                int row = mi * 16 + r16;
                int ch = (kh * 4 + q) ^ (row & 7);
                af[mi] = *(const bf16x8*)&lA[row * 64 + ch * 8];
            }
#pragma unroll
            for (int ni = 0; ni < 2; ni++) {
                int row = w * 32 + ni * 16 + r16;
                int ch = (kh * 4 + q) ^ (row & 7);
                gf[ni] = *(const bf16x8*)&lG[row * 64 + ch * 8];
                uf[ni] = *(const bf16x8*)&lU[row * 64 + ch * 8];
            }
#pragma unroll
            for (int mi = 0; mi < 4; mi++)
#pragma unroll
                for (int ni = 0; ni < 2; ni++) {
                    accg[mi][ni] = __builtin_amdgcn_mfma_f32_16x16x32_bf16(af[mi], gf[ni], accg[mi][ni], 0, 0, 0);
                    accu[mi][ni] = __builtin_amdgcn_mfma_f32_16x16x32_bf16(af[mi], uf[ni], accu[mi][ni], 0, 0, 0);
                }
        }
        __syncthreads();
    }

    // epilogue: C/D mapping col=lane&15, row=(lane>>4)*4+reg
#pragma unroll
    for (int mi = 0; mi < 4; mi++) {
#pragma unroll
        for (int r = 0; r < 4; r++) {
            int row = mi * 16 + q * 4 + r;
            int gr = m0 + row;
            if (gr < cnt) {
                float wt = routed ? tw[e * T_TOK + gr] : 1.0f;
                u16* hrow = hout + (size_t)(hbase + gr) * I_DIM + n0 + w * 32;
#pragma unroll
                for (int ni = 0; ni < 2; ni++) {
                    float g = accg[mi][ni][r], u = accu[mi][ni][r];
                    float hv = (g / (1.f + __expf(-g))) * u * wt;
                    hrow[ni * 16 + r16] = f2bf(hv);
                }
            }
        }
    }
}

// down: tile 64(M) x 128(N) x 64(K); 4 waves own full M, 32-wide N slices; atomicAdd out.
__global__ __launch_bounds__(256, 3)
void down_bf(const u16* __restrict__ h_r, const u16* __restrict__ h_s,
             const u16* __restrict__ edw, const u16* __restrict__ sdw,
             const int* __restrict__ counts, const int* __restrict__ tok,
             float* __restrict__ out) {
    __shared__ u16 lA[64 * 64];    // 8 KB
    __shared__ u16 lB[128 * 64];   // 16 KB

    int e = blockIdx.z;
    bool routed = (e < NEXP);
    int cnt, hbase; const u16* Wd; const u16* hin;
    if (routed) {
        cnt = counts[e];
        int p = 0;
#pragma unroll
        for (int i = 0; i < NEXP; i++) { int c = counts[i]; if (i < e) p += c; }
        hbase = p;
        Wd = edw + (size_t)e * H_DIM * I_DIM;
        hin = h_r;
    } else { cnt = T_TOK; hbase = 0; Wd = sdw; hin = h_s; }
    int m0 = blockIdx.y * 64;
    if (m0 >= cnt) return;
    int n0 = blockIdx.x * 128;

    int tid = threadIdx.x, lane = tid & 63, w = tid >> 6;

    const u16* aptr[2]; u16* alds[2];
#pragma unroll
    for (int j = 0; j < 2; j++) {
        int chunk = w * 128 + j * 64 + lane;
        int row = chunk >> 3, cl = chunk & 7;
        int cg = cl ^ (row & 7);
        int hr = m0 + row; if (hr > cnt - 1) hr = cnt - 1;
        aptr[j] = hin + (size_t)(hbase + hr) * I_DIM + cg * 8;
        alds[j] = &lA[(w * 128 + j * 64) * 8];
    }
    const u16* bptr[4]; u16* blds[4];
#pragma unroll
    for (int j = 0; j < 4; j++) {
        int chunk = w * 256 + j * 64 + lane;
        int row = chunk >> 3, cl = chunk & 7;
        int cg = cl ^ (row & 7);
        bptr[j] = Wd + (size_t)(n0 + row) * I_DIM + cg * 8;
        blds[j] = &lB[(w * 256 + j * 64) * 8];
    }

    f32x4 zero = {0.f, 0.f, 0.f, 0.f};
    f32x4 acc[4][2];
#pragma unroll
    for (int a = 0; a < 4; a++)
#pragma unroll
        for (int b = 0; b < 2; b++) acc[a][b] = zero;

    int r16 = lane & 15, q = lane >> 4;

    for (int k0 = 0; k0 < I_DIM; k0 += 64) {  // 1408 = 22*64
#pragma unroll
        for (int j = 0; j < 2; j++) g2l16(aptr[j] + k0, alds[j]);
#pragma unroll
        for (int j = 0; j < 4; j++) g2l16(bptr[j] + k0, blds[j]);
        __syncthreads();
#pragma unroll
        for (int kh = 0; kh < 2; kh++) {
            bf16x8 af[4], bfr[2];
#pragma unroll
            for (int mi = 0; mi < 4; mi++) {
                int row = mi * 16 + r16;
                int ch = (kh * 4 + q) ^ (row & 7);
                af[mi] = *(const bf16x8*)&lA[row * 64 + ch * 8];
            }
#pragma unroll
            for (int ni = 0; ni < 2; ni++) {
                int row = w * 32 + ni * 16 + r16;
                int ch = (kh * 4 + q) ^ (row & 7);
                bfr[ni] = *(const bf16x8*)&lB[row * 64 + ch * 8];
            }
#pragma unroll
            for (int mi = 0; mi < 4; mi++)
#pragma unroll
                for (int ni = 0; ni < 2; ni++)
                    acc[mi][ni] = __builtin_amdgcn_mfma_f32_16x16x32_bf16(af[mi], bfr[ni], acc[mi][ni], 0, 0, 0);
        }
        __syncthreads();
    }

#pragma unroll
    for (int mi = 0; mi < 4; mi++) {
#pragma unroll
        for (int r = 0; r < 4; r++) {
            int row = mi * 16 + q * 4 + r;
            int gr = m0 + row;
            if (gr < cnt) {
                int t = routed ? tok[e * T_TOK + gr] : gr;
                float* orow = out + (size_t)t * H_DIM + n0 + w * 32;
#pragma unroll
                for (int ni = 0; ni < 2; ni++)
                    atomicAdd(&orow[ni * 16 + r16], acc[mi][ni][r]);
            }
        }
    }
}

// ================= FALLBACK PATH (round-2 fp32 kernels, used only if ws too small) =================
__global__ __launch_bounds__(256, 2)
void gate_up_f32(const float* __restrict__ x,
                 const float* __restrict__ egw, const float* __restrict__ euw,
                 const float* __restrict__ sgw, const float* __restrict__ suw,
                 const int* __restrict__ counts, const int* __restrict__ tok,
                 const float* __restrict__ tw,
                 u16* __restrict__ h_r, u16* __restrict__ h_s) {
    __shared__ u16 lA[64 * LS];
    __shared__ u16 lG[128 * LS];
    __shared__ u16 lU[128 * LS];
    int e = blockIdx.z;
    bool routed = (e < NEXP);
    int cnt, hbase; const float *Wg, *Wu; u16* hout;
    if (routed) {
        cnt = counts[e];
        int p = 0;
#pragma unroll
        for (int i = 0; i < NEXP; i++) { int c = counts[i]; if (i < e) p += c; }
        hbase = p;
        Wg = egw + (size_t)e * I_DIM * H_DIM; Wu = euw + (size_t)e * I_DIM * H_DIM; hout = h_r;
    } else { cnt = T_TOK; hbase = 0; Wg = sgw; Wu = suw; hout = h_s; }
    int m0 = blockIdx.y * 64;
    if (m0 >= cnt) return;
    int n0 = blockIdx.x * 128;
    int tid = threadIdx.x, lane = tid & 63, w = tid >> 6;
    const float* ap[2]; int sa[2];
#pragma unroll
    for (int i = 0; i < 2; i++) {
        int slot = tid + i * 256;
        int row = slot >> 3, c4 = slot & 7;
        sa[i] = row * LS + c4 * 4;
        int trow = m0 + row; if (trow > cnt - 1) trow = cnt - 1;
        int tix = routed ? tok[e * T_TOK + trow] : trow;
        ap[i] = x + (size_t)tix * H_DIM + c4 * 4;
    }
    const float* gp[4]; const float* up[4]; int sg[4];
#pragma unroll
    for (int i = 0; i < 4; i++) {
        int slot = tid + i * 256;
        int row = slot >> 3, c4 = slot & 7;
        sg[i] = row * LS + c4 * 4;
        gp[i] = Wg + (size_t)(n0 + row) * H_DIM + c4 * 4;
        up[i] = Wu + (size_t)(n0 + row) * H_DIM + c4 * 4;
    }
    f32x4 zero = {0.f, 0.f, 0.f, 0.f};
    f32x4 accg[4][2], accu[4][2];
#pragma unroll
    for (int a = 0; a < 4; a++)
#pragma unroll
        for (int b = 0; b < 2; b++) { accg[a][b] = zero; accu[a][b] = zero; }
    int r16 = lane & 15, kq = lane >> 4;
    float4 ra[2], rg[4], ru[4];
#pragma unroll
    for (int i = 0; i < 2; i++) ra[i] = *(const float4*)(ap[i]);
#pragma unroll
    for (int i = 0; i < 4; i++) { rg[i] = *(const float4*)(gp[i]); ru[i] = *(const float4*)(up[i]); }
    for (int k0 = 0; k0 < H_DIM; k0 += 32) {
#pragma unroll
        for (int i = 0; i < 2; i++) *(uint2*)&lA[sa[i]] = pack4(ra[i]);
#pragma unroll
        for (int i = 0; i < 4; i++) { *(uint2*)&lG[sg[i]] = pack4(rg[i]); *(uint2*)&lU[sg[i]] = pack4(ru[i]); }
        __syncthreads();
        if (k0 + 32 < H_DIM) {
            int kn = k0 + 32;
#pragma unroll
            for (int i = 0; i < 2; i++) ra[i] = *(const float4*)(ap[i] + kn);
#pragma unroll
            for (int i = 0; i < 4; i++) { rg[i] = *(const float4*)(gp[i] + kn); ru[i] = *(const float4*)(up[i] + kn); }
        }
        bf16x8 af[4], gf[2], uf[2];
#pragma unroll
        for (int mi = 0; mi < 4; mi++) af[mi] = *(const bf16x8*)&lA[(mi * 16 + r16) * LS + kq * 8];
#pragma unroll
        for (int ni = 0; ni < 2; ni++) {
            gf[ni] = *(const bf16x8*)&lG[(w * 32 + ni * 16 + r16) * LS + kq * 8];
            uf[ni] = *(const bf16x8*)&lU[(w * 32 + ni * 16 + r16) * LS + kq * 8];
        }
#pragma unroll
        for (int mi = 0; mi < 4; mi++)
#pragma unroll
            for (int ni = 0; ni < 2; ni++) {
                accg[mi][ni] = __builtin_amdgcn_mfma_f32_16x16x32_bf16(af[mi], gf[ni], accg[mi][ni], 0, 0, 0);
                accu[mi][ni] = __builtin_amdgcn_mfma_f32_16x16x32_bf16(af[mi], uf[ni], accu[mi][ni], 0, 0, 0);
            }
        __syncthreads();
    }
#pragma unroll
    for (int mi = 0; mi < 4; mi++) {
#pragma unroll
        for (int r = 0; r < 4; r++) {
            int row = mi * 16 + kq * 4 + r;
            int gr = m0 + row;
            if (gr < cnt) {
                float wt = routed ? tw[e * T_TOK + gr] : 1.0f;
                u16* hrow = hout + (size_t)(hbase + gr) * I_DIM + n0 + w * 32;
#pragma unroll
                for (int ni = 0; ni < 2; ni++) {
                    float g = accg[mi][ni][r], u = accu[mi][ni][r];
                    float hv = (g / (1.f + __expf(-g))) * u * wt;
                    hrow[ni * 16 + r16] = f2bf(hv);
                }
            }
        }
    }
}

__global__ __launch_bounds__(256, 2)
void down_f32(const u16* __restrict__ h_r, const u16* __restrict__ h_s,
              const float* __restrict__ edw, const float* __restrict__ sdw,
              const int* __restrict__ counts, const int* __restrict__ tok,
              float* __restrict__ out) {
    __shared__ u16 lA[64 * LS];
    __shared__ u16 lB[128 * LS];
    int e = blockIdx.z;
    bool routed = (e < NEXP);
    int cnt, hbase; const float* Wd; const u16* hin;
    if (routed) {
        cnt = counts[e];
        int p = 0;
#pragma unroll
        for (int i = 0; i < NEXP; i++) { int c = counts[i]; if (i < e) p += c; }
        hbase = p;
        Wd = edw + (size_t)e * H_DIM * I_DIM; hin = h_r;
    } else { cnt = T_TOK; hbase = 0; Wd = sdw; hin = h_s; }
    int m0 = blockIdx.y * 64;
    if (m0 >= cnt) return;
    int n0 = blockIdx.x * 128;
    int tid = threadIdx.x, lane = tid & 63, w = tid >> 6;
    int arow = tid >> 2, ac8 = tid & 3;
    int hr = m0 + arow; if (hr > cnt - 1) hr = cnt - 1;
    const u16* ap = hin + (size_t)(hbase + hr) * I_DIM + ac8 * 8;
    int sa = arow * LS + ac8 * 8;
    const float* bp[4]; int sb[4];
#pragma unroll
    for (int i = 0; i < 4; i++) {
        int slot = tid + i * 256;
        int row = slot >> 3, c4 = slot & 7;
        bp[i] = Wd + (size_t)(n0 + row) * I_DIM + c4 * 4;
        sb[i] = row * LS + c4 * 4;
    }
    f32x4 zero = {0.f, 0.f, 0.f, 0.f};
    f32x4 acc[4][2];
#pragma unroll
    for (int a = 0; a < 4; a++)
#pragma unroll
        for (int b = 0; b < 2; b++) acc[a][b] = zero;
    int r16 = lane & 15, kq = lane >> 4;
    uint4 ra = *(const uint4*)(ap);
    float4 rb[4];
#pragma unroll
    for (int i = 0; i < 4; i++) rb[i] = *(const float4*)(bp[i]);
    for (int k0 = 0; k0 < I_DIM; k0 += 32) {
        *(uint4*)&lA[sa] = ra;
#pragma unroll
        for (int i = 0; i < 4; i++) *(uint2*)&lB[sb[i]] = pack4(rb[i]);
        __syncthreads();
        if (k0 + 32 < I_DIM) {
            int kn = k0 + 32;
            ra = *(const uint4*)(ap + kn);
#pragma unroll
            for (int i = 0; i < 4; i++) rb[i] = *(const float4*)(bp[i] + kn);
        }
        bf16x8 af[4], bfr[2];
#pragma unroll
        for (int mi = 0; mi < 4; mi++) af[mi] = *(const bf16x8*)&lA[(mi * 16 + r16) * LS + kq * 8];
#pragma unroll
        for (int ni = 0; ni < 2; ni++) bfr[ni] = *(const bf16x8*)&lB[(w * 32 + ni * 16 + r16) * LS + kq * 8];
#pragma unroll
        for (int mi = 0; mi < 4; mi++)
#pragma unroll
            for (int ni = 0; ni < 2; ni++)
                acc[mi][ni] = __builtin_amdgcn_mfma_f32_16x16x32_bf16(af[mi], bfr[ni], acc[mi][ni], 0, 0, 0);
        __syncthreads();
    }
#pragma unroll
    for (int mi = 0; mi < 4; mi++) {
#pragma unroll
        for (int r = 0; r < 4; r++) {
            int row = mi * 16 + kq * 4 + r;
            int gr = m0 + row;
            if (gr < cnt) {
                int t = routed ? tok[e * T_TOK + gr] : gr;
                float* orow = out + (size_t)t * H_DIM + n0 + w * 32;
#pragma unroll
                for (int ni = 0; ni < 2; ni++)
                    atomicAdd(&orow[ni * 16 + r16], acc[mi][ni][r]);
            }
        }
    }
}

extern "C" void kernel_launch(void* const* d_in, const int* in_sizes, int n_in,
                              void* d_out, int out_size, void* d_ws, size_t ws_size,
                              hipStream_t stream) {
    const float* x   = (const float*)d_in[0];
    const float* gw  = (const float*)d_in[1];
    const float* egw = (const float*)d_in[2];
    const float* euw = (const float*)d_in[3];
    const float* edw = (const float*)d_in[4];
    const float* sgw = (const float*)d_in[5];
    const float* suw = (const float*)d_in[6];
    const float* sdw = (const float*)d_in[7];
    float* out = (float*)d_out;

    char* ws = (char*)d_ws;
    int*   counts = (int*)ws;
    int*   tok    = (int*)(ws + 256);
    float* tw     = (float*)(ws + 256 + 32768);
    u16*   h_r    = (u16*)(ws + 65792);
    u16*   h_s    = h_r + (size_t)2048 * I_DIM;

    hipMemsetAsync(counts, 0, 32, stream);
    hipMemsetAsync(out, 0, (size_t)T_TOK * H_DIM * sizeof(float), stream);
    router_kernel<<<256, 256, 0, stream>>>(x, gw, counts, tok, tw);

    const size_t NEED = 168624384ull;  // bf16 weight copies + h buffers
    if (ws_size >= NEED) {
        u16* xbf = (u16*)(ws + 8716544);
        u16* egb = (u16*)(ws + 12910848);
        u16* eub = (u16*)(ws + 59048192);
        u16* edb = (u16*)(ws + 105185536);
        u16* sgb = (u16*)(ws + 151322880);
        u16* sub = (u16*)(ws + 157090048);
        u16* sdb = (u16*)(ws + 162857216);
        Cvt7 c;
        c.in[0] = egw; c.out[0] = egb; c.nchunk[0] = 2883584;
        c.in[1] = euw; c.out[1] = eub; c.nchunk[1] = 2883584;
        c.in[2] = edw; c.out[2] = edb; c.nchunk[2] = 2883584;
        c.in[3] = sgw; c.out[3] = sgb; c.nchunk[3] = 360448;
        c.in[4] = suw; c.out[4] = sub; c.nchunk[4] = 360448;
        c.in[5] = sdw; c.out[5] = sdb; c.nchunk[5] = 360448;
        c.in[6] = x;   c.out[6] = xbf; c.nchunk[6] = 262144;
        convert_bf<<<dim3(2048, 1, 7), 256, 0, stream>>>(c);
        gate_up_bf<<<dim3(11, 16, 9), 256, 0, stream>>>(xbf, egb, eub, sgb, sub, counts, tok, tw, h_r, h_s);
        down_bf<<<dim3(16, 16, 9), 256, 0, stream>>>(h_r, h_s, edb, sdb, counts, tok, out);
    } else {
        gate_up_f32<<<dim3(11, 16, 9), 256, 0, stream>>>(x, egw, euw, sgw, suw, counts, tok, tw, h_r, h_s);
        down_f32<<<dim3(16, 16, 9), 256, 0, stream>>>(h_r, h_s, edw, sdw, counts, tok, out);
    }
}

// Round 4
// 503.952 us; speedup vs baseline: 1.3313x; 1.0392x over previous
//
#include <hip/hip_runtime.h>
#include <hip/hip_bf16.h>

typedef unsigned short u16;
typedef __bf16 bf16x8 __attribute__((ext_vector_type(8)));
typedef float f32x4 __attribute__((ext_vector_type(4)));

#define H_DIM 2048
#define I_DIM 1408
#define T_TOK 1024
#define NEXP 8
#define LS 40  // fallback-path LDS stride

__device__ __forceinline__ u16 f2bf(float f) {
    union { float f; unsigned u; } v; v.f = f;
    unsigned r = v.u + 0x7FFFu + ((v.u >> 16) & 1u);  // RNE
    return (u16)(r >> 16);
}
__device__ __forceinline__ unsigned pack2(float a, float b) {
    float2 t; t.x = a; t.y = b;
    __hip_bfloat162 h = __float22bfloat162_rn(t);  // v_cvt_pk_bf16_f32
    union { __hip_bfloat162 h; unsigned u; } v; v.h = h;
    return v.u;
}
__device__ __forceinline__ uint2 pack4(float4 f) {
    uint2 r; r.x = pack2(f.x, f.y); r.y = pack2(f.z, f.w); return r;
}
__device__ __forceinline__ void g2l16(const void* g, void* l) {
    __builtin_amdgcn_global_load_lds((const __attribute__((address_space(1))) void*)g,
                                     (__attribute__((address_space(3))) void*)l, 16, 0, 0);
}

// ============ prep: fused weight-convert (z<6) + router/x-convert (z==6) ============
struct PrepArgs {
    const float* cin[6]; u16* cout[6]; int n16[6];
    const float* x; const float* gw; u16* xb;
    int* counts; int* tok; float* tw; unsigned* tslot;
};

__global__ __launch_bounds__(256)
void prep_kernel(PrepArgs a) {
    int z = blockIdx.z;
    if (z < 6) {
        int n = a.n16[z];
        const float4* in = (const float4*)a.cin[z];
        uint4* out = (uint4*)a.cout[z];
        for (int i = blockIdx.x * 256 + threadIdx.x; i < n; i += gridDim.x * 256) {
            const float4* p = in + (size_t)i * 4;
            float4 f0 = p[0], f1 = p[1], f2 = p[2], f3 = p[3];
            uint4 o0, o1;
            o0.x = pack2(f0.x, f0.y); o0.y = pack2(f0.z, f0.w);
            o0.z = pack2(f1.x, f1.y); o0.w = pack2(f1.z, f1.w);
            o1.x = pack2(f2.x, f2.y); o1.y = pack2(f2.z, f2.w);
            o1.z = pack2(f3.x, f3.y); o1.w = pack2(f3.z, f3.w);
            out[(size_t)i * 2]     = o0;
            out[(size_t)i * 2 + 1] = o1;
        }
    } else {
        if (blockIdx.x >= 256) return;
        int wave = threadIdx.x >> 6, lane = threadIdx.x & 63;
        int t = blockIdx.x * 4 + wave;
        const float4* xr = (const float4*)(a.x + (size_t)t * H_DIM);
        const float4* gw4 = (const float4*)a.gw;
        uint2* xbr = (uint2*)(a.xb + (size_t)t * H_DIM);
        float acc[NEXP];
#pragma unroll
        for (int e = 0; e < NEXP; e++) acc[e] = 0.f;
#pragma unroll
        for (int j = 0; j < 8; j++) {
            int c = lane + j * 64;
            float4 xv = xr[c];
            xbr[c] = pack4(xv);
#pragma unroll
            for (int e = 0; e < NEXP; e++) {
                float4 gv = gw4[e * 512 + c];
                acc[e] += xv.x * gv.x + xv.y * gv.y + xv.z * gv.z + xv.w * gv.w;
            }
        }
#pragma unroll
        for (int e = 0; e < NEXP; e++) {
#pragma unroll
            for (int off = 32; off > 0; off >>= 1) acc[e] += __shfl_xor(acc[e], off);
        }
        if (lane == 0) {
            int i0 = 0; float v0 = acc[0];
#pragma unroll
            for (int e = 1; e < NEXP; e++) if (acc[e] > v0) { v0 = acc[e]; i0 = e; }
            int i1 = -1; float v1 = -3.0e38f;
#pragma unroll
            for (int e = 0; e < NEXP; e++) if (e != i0 && acc[e] > v1) { v1 = acc[e]; i1 = e; }
            float ex = __expf(v1 - v0);
            float w0 = 1.f / (1.f + ex);
            float w1 = 1.f - w0;
            int s0 = atomicAdd(&a.counts[i0], 1);
            a.tok[i0 * T_TOK + s0] = t; a.tw[i0 * T_TOK + s0] = w0;
            a.tslot[t * 2] = ((unsigned)i0 << 16) | (unsigned)s0;
            int s1 = atomicAdd(&a.counts[i1], 1);
            a.tok[i1 * T_TOK + s1] = t; a.tw[i1 * T_TOK + s1] = w1;
            a.tslot[t * 2 + 1] = ((unsigned)i1 << 16) | (unsigned)s1;
        }
    }
}

// ============ gate+up GEMM: 2 waves/block, block 64Mx128N, wave 64x64, BK=64 ============
__global__ __launch_bounds__(128, 2)
void gate_up_bf(const u16* __restrict__ xb,
                const u16* __restrict__ egb, const u16* __restrict__ eub,
                const u16* __restrict__ sgb, const u16* __restrict__ sub,
                const int* __restrict__ counts, const int* __restrict__ tok,
                const float* __restrict__ tw,
                u16* __restrict__ h_r, u16* __restrict__ h_s) {
    __shared__ u16 lA[64 * 64];    // 8 KB
    __shared__ u16 lG[128 * 64];   // 16 KB
    __shared__ u16 lU[128 * 64];   // 16 KB

    int e = blockIdx.z;
    bool routed = (e < NEXP);
    int cnt, hbase; const u16 *Wg, *Wu; u16* hout;
    if (routed) {
        cnt = counts[e];
        int p = 0;
#pragma unroll
        for (int i = 0; i < NEXP; i++) { int c = counts[i]; if (i < e) p += c; }
        hbase = p;
        Wg = egb + (size_t)e * I_DIM * H_DIM;
        Wu = eub + (size_t)e * I_DIM * H_DIM;
        hout = h_r;
    } else { cnt = T_TOK; hbase = 0; Wg = sgb; Wu = sub; hout = h_s; }
    int m0 = blockIdx.y * 64;
    if (m0 >= cnt) return;
    int n0 = blockIdx.x * 128;

    int tid = threadIdx.x, lane = tid & 63, w = tid >> 6;  // w in {0,1}
    int l3 = lane >> 3, cl = lane & 7;
    int cg = cl ^ l3;  // swizzled global chunk for this lane (row&7 == l3 for all groups)

    // A: 64 rows x 8 chunks; wave w group j covers rows w*32+j*8+l3
    const u16* aptr[4];
#pragma unroll
    for (int j = 0; j < 4; j++) {
        int row = w * 32 + j * 8 + l3;
        int trow = m0 + row; if (trow > cnt - 1) trow = cnt - 1;
        int tix = routed ? tok[e * T_TOK + trow] : trow;
        aptr[j] = xb + (size_t)tix * H_DIM + cg * 8;
    }
    // G/U: 128 rows; wave w group j covers rows n0 + w*64 + j*8 + l3  (I_DIM = 11*128 exact)
    const u16* gbase = Wg + (size_t)(n0 + w * 64 + l3) * H_DIM + cg * 8;
    const u16* ubase = Wu + (size_t)(n0 + w * 64 + l3) * H_DIM + cg * 8;

    u16* aldsb = &lA[w * 2048];
    u16* gldsb = &lG[w * 4096];
    u16* uldsb = &lU[w * 4096];

    f32x4 zero = {0.f, 0.f, 0.f, 0.f};
    f32x4 accg[4][4], accu[4][4];
#pragma unroll
    for (int a = 0; a < 4; a++)
#pragma unroll
        for (int b = 0; b < 4; b++) { accg[a][b] = zero; accu[a][b] = zero; }

    int r16 = lane & 15, q = lane >> 4;

    for (int k0 = 0; k0 < H_DIM; k0 += 64) {
#pragma unroll
        for (int j = 0; j < 4; j++) g2l16(aptr[j] + k0, aldsb + j * 512);
#pragma unroll
        for (int j = 0; j < 8; j++) {
            g2l16(gbase + (size_t)j * 8 * H_DIM + k0, gldsb + j * 512);
            g2l16(ubase + (size_t)j * 8 * H_DIM + k0, uldsb + j * 512);
        }
        __syncthreads();
#pragma unroll
        for (int kh = 0; kh < 2; kh++) {
            bf16x8 af[4], gf[4], uf[4];
#pragma unroll
            for (int mi = 0; mi < 4; mi++) {
                int row = mi * 16 + r16;
                int ch = (kh * 4 + q) ^ (row & 7);
                af[mi] = *(const bf16x8*)&lA[row * 64 + ch * 8];
            }
#pragma unroll
            for (int ni = 0; ni < 4; ni++) {
                int row = w * 64 + ni * 16 + r16;
                int ch = (kh * 4 + q) ^ (row & 7);
                gf[ni] = *(const bf16x8*)&lG[row * 64 + ch * 8];
                uf[ni] = *(const bf16x8*)&lU[row * 64 + ch * 8];
            }
#pragma unroll
            for (int mi = 0; mi < 4; mi++)
#pragma unroll
                for (int ni = 0; ni < 4; ni++) {
                    accg[mi][ni] = __builtin_amdgcn_mfma_f32_16x16x32_bf16(af[mi], gf[ni], accg[mi][ni], 0, 0, 0);
                    accu[mi][ni] = __builtin_amdgcn_mfma_f32_16x16x32_bf16(af[mi], uf[ni], accu[mi][ni], 0, 0, 0);
                }
        }
        __syncthreads();
    }

    // epilogue: C/D col=lane&15, row=(lane>>4)*4+reg
#pragma unroll
    for (int mi = 0; mi < 4; mi++) {
#pragma unroll
        for (int r = 0; r < 4; r++) {
            int row = mi * 16 + q * 4 + r;
            int gr = m0 + row;
            if (gr < cnt) {
                float wt = routed ? tw[e * T_TOK + gr] : 1.0f;
                u16* hrow = hout + (size_t)(hbase + gr) * I_DIM + n0 + w * 64;
#pragma unroll
                for (int ni = 0; ni < 4; ni++) {
                    float g = accg[mi][ni][r], u = accu[mi][ni][r];
                    hrow[ni * 16 + r16] = f2bf((g / (1.f + __expf(-g))) * u * wt);
                }
            }
        }
    }
}

// ============ down GEMM: 2 waves/block, 64Mx128N, wave 64x64, BK=64; plain fp32 stores ============
__global__ __launch_bounds__(128, 2)
void down_bf(const u16* __restrict__ h_r, const u16* __restrict__ h_s,
             const u16* __restrict__ edb, const u16* __restrict__ sdb,
             const int* __restrict__ counts, const int* __restrict__ tok,
             float* __restrict__ y_r, float* __restrict__ y_s) {
    __shared__ u16 lA[64 * 64];    // 8 KB
    __shared__ u16 lB[128 * 64];   // 16 KB

    int e = blockIdx.z;
    bool routed = (e < NEXP);
    int cnt, hbase; const u16* Wd; const u16* hin;
    if (routed) {
        cnt = counts[e];
        int p = 0;
#pragma unroll
        for (int i = 0; i < NEXP; i++) { int c = counts[i]; if (i < e) p += c; }
        hbase = p;
        Wd = edb + (size_t)e * H_DIM * I_DIM;
        hin = h_r;
    } else { cnt = T_TOK; hbase = 0; Wd = sdb; hin = h_s; }
    int m0 = blockIdx.y * 64;
    if (m0 >= cnt) return;
    int n0 = blockIdx.x * 128;

    int tid = threadIdx.x, lane = tid & 63, w = tid >> 6;
    int l3 = lane >> 3, cl = lane & 7;
    int cg = cl ^ l3;

    const u16* aptr[4];
#pragma unroll
    for (int j = 0; j < 4; j++) {
        int row = w * 32 + j * 8 + l3;
        int hr = m0 + row; if (hr > cnt - 1) hr = cnt - 1;
        aptr[j] = hin + (size_t)(hbase + hr) * I_DIM + cg * 8;
    }
    const u16* bbase = Wd + (size_t)(n0 + w * 64 + l3) * I_DIM + cg * 8;  // H_DIM = 16*128 exact

    u16* aldsb = &lA[w * 2048];
    u16* bldsb = &lB[w * 4096];

    f32x4 zero = {0.f, 0.f, 0.f, 0.f};
    f32x4 acc[4][4];
#pragma unroll
    for (int a = 0; a < 4; a++)
#pragma unroll
        for (int b = 0; b < 4; b++) acc[a][b] = zero;

    int r16 = lane & 15, q = lane >> 4;

    for (int k0 = 0; k0 < I_DIM; k0 += 64) {  // 1408 = 22*64
#pragma unroll
        for (int j = 0; j < 4; j++) g2l16(aptr[j] + k0, aldsb + j * 512);
#pragma unroll
        for (int j = 0; j < 8; j++) g2l16(bbase + (size_t)j * 8 * I_DIM + k0, bldsb + j * 512);
        __syncthreads();
#pragma unroll
        for (int kh = 0; kh < 2; kh++) {
            bf16x8 af[4], bfr[4];
#pragma unroll
            for (int mi = 0; mi < 4; mi++) {
                int row = mi * 16 + r16;
                int ch = (kh * 4 + q) ^ (row & 7);
                af[mi] = *(const bf16x8*)&lA[row * 64 + ch * 8];
            }
#pragma unroll
            for (int ni = 0; ni < 4; ni++) {
                int row = w * 64 + ni * 16 + r16;
                int ch = (kh * 4 + q) ^ (row & 7);
                bfr[ni] = *(const bf16x8*)&lB[row * 64 + ch * 8];
            }
#pragma unroll
            for (int mi = 0; mi < 4; mi++)
#pragma unroll
                for (int ni = 0; ni < 4; ni++)
                    acc[mi][ni] = __builtin_amdgcn_mfma_f32_16x16x32_bf16(af[mi], bfr[ni], acc[mi][ni], 0, 0, 0);
        }
        __syncthreads();
    }

#pragma unroll
    for (int mi = 0; mi < 4; mi++) {
#pragma unroll
        for (int r = 0; r < 4; r++) {
            int row = mi * 16 + q * 4 + r;
            int gr = m0 + row;
            if (gr < cnt) {
                float* yrow = (routed ? y_r + (size_t)(hbase + gr) * H_DIM
                                      : y_s + (size_t)gr * H_DIM) + n0 + w * 64;
#pragma unroll
                for (int ni = 0; ni < 4; ni++)
                    yrow[ni * 16 + r16] = acc[mi][ni][r];
            }
        }
    }
}

// ============ reduce: out[t] = y_s[t] + y_r[slot0(t)] + y_r[slot1(t)] ============
__global__ __launch_bounds__(256)
void reduce_kernel(const int* __restrict__ counts, const unsigned* __restrict__ tslot,
                   const float* __restrict__ y_r, const float* __restrict__ y_s,
                   float* __restrict__ out) {
    int t = blockIdx.x;
    int pre[NEXP]; int run = 0;
#pragma unroll
    for (int i = 0; i < NEXP; i++) { pre[i] = run; run += counts[i]; }
    unsigned t0 = tslot[t * 2], t1 = tslot[t * 2 + 1];
    int r0 = pre[t0 >> 16] + (int)(t0 & 0xffffu);
    int r1 = pre[t1 >> 16] + (int)(t1 & 0xffffu);
    const float4* ys = (const float4*)(y_s + (size_t)t * H_DIM);
    const float4* a0 = (const float4*)(y_r + (size_t)r0 * H_DIM);
    const float4* a1 = (const float4*)(y_r + (size_t)r1 * H_DIM);
    float4* o = (float4*)(out + (size_t)t * H_DIM);
#pragma unroll
    for (int j = 0; j < 2; j++) {
        int c = threadIdx.x + j * 256;  // 512 float4 per row
        float4 s = ys[c], b0 = a0[c], b1 = a1[c];
        float4 r;
        r.x = s.x + b0.x + b1.x; r.y = s.y + b0.y + b1.y;
        r.z = s.z + b0.z + b1.z; r.w = s.w + b0.w + b1.w;
        o[c] = r;
    }
}

// ================= FALLBACK PATH (fp32, only if ws too small) =================
__global__ __launch_bounds__(256)
void router_kernel(const float* __restrict__ x, const float* __restrict__ gw,
                   int* __restrict__ counts, int* __restrict__ tok, float* __restrict__ tw) {
    int wave = threadIdx.x >> 6;
    int lane = threadIdx.x & 63;
    int t = blockIdx.x * 4 + wave;
    const float* xr = x + (size_t)t * H_DIM;
    float acc[NEXP];
#pragma unroll
    for (int e = 0; e < NEXP; e++) acc[e] = 0.f;
    for (int h = lane; h < H_DIM; h += 64) {
        float xv = xr[h];
#pragma unroll
        for (int e = 0; e < NEXP; e++) acc[e] += xv * gw[e * H_DIM + h];
    }
#pragma unroll
    for (int e = 0; e < NEXP; e++) {
#pragma unroll
        for (int off = 32; off > 0; off >>= 1) acc[e] += __shfl_xor(acc[e], off);
    }
    if (lane == 0) {
        int i0 = 0; float v0 = acc[0];
#pragma unroll
        for (int e = 1; e < NEXP; e++) if (acc[e] > v0) { v0 = acc[e]; i0 = e; }
        int i1 = -1; float v1 = -3.0e38f;
#pragma unroll
        for (int e = 0; e < NEXP; e++) if (e != i0 && acc[e] > v1) { v1 = acc[e]; i1 = e; }
        float ex = __expf(v1 - v0);
        float w0 = 1.f / (1.f + ex);
        float w1 = 1.f - w0;
        int s0 = atomicAdd(&counts[i0], 1);
        tok[i0 * T_TOK + s0] = t; tw[i0 * T_TOK + s0] = w0;
        int s1 = atomicAdd(&counts[i1], 1);
        tok[i1 * T_TOK + s1] = t; tw[i1 * T_TOK + s1] = w1;
    }
}

__global__ __launch_bounds__(256, 2)
void gate_up_f32(const float* __restrict__ x,
                 const float* __restrict__ egw, const float* __restrict__ euw,
                 const float* __restrict__ sgw, const float* __restrict__ suw,
                 const int* __restrict__ counts, const int* __restrict__ tok,
                 const float* __restrict__ tw,
                 u16* __restrict__ h_r, u16* __restrict__ h_s) {
    __shared__ u16 lA[64 * LS];
    __shared__ u16 lG[128 * LS];
    __shared__ u16 lU[128 * LS];
    int e = blockIdx.z;
    bool routed = (e < NEXP);
    int cnt, hbase; const float *Wg, *Wu; u16* hout;
    if (routed) {
        cnt = counts[e];
        int p = 0;
#pragma unroll
        for (int i = 0; i < NEXP; i++) { int c = counts[i]; if (i < e) p += c; }
        hbase = p;
        Wg = egw + (size_t)e * I_DIM * H_DIM; Wu = euw + (size_t)e * I_DIM * H_DIM; hout = h_r;
    } else { cnt = T_TOK; hbase = 0; Wg = sgw; Wu = suw; hout = h_s; }
    int m0 = blockIdx.y * 64;
    if (m0 >= cnt) return;
    int n0 = blockIdx.x * 128;
    int tid = threadIdx.x, lane = tid & 63, w = tid >> 6;
    const float* ap[2]; int sa[2];
#pragma unroll
    for (int i = 0; i < 2; i++) {
        int slot = tid + i * 256;
        int row = slot >> 3, c4 = slot & 7;
        sa[i] = row * LS + c4 * 4;
        int trow = m0 + row; if (trow > cnt - 1) trow = cnt - 1;
        int tix = routed ? tok[e * T_TOK + trow] : trow;
        ap[i] = x + (size_t)tix * H_DIM + c4 * 4;
    }
    const float* gp[4]; const float* up[4]; int sg[4];
#pragma unroll
    for (int i = 0; i < 4; i++) {
        int slot = tid + i * 256;
        int row = slot >> 3, c4 = slot & 7;
        sg[i] = row * LS + c4 * 4;
        gp[i] = Wg + (size_t)(n0 + row) * H_DIM + c4 * 4;
        up[i] = Wu + (size_t)(n0 + row) * H_DIM + c4 * 4;
    }
    f32x4 zero = {0.f, 0.f, 0.f, 0.f};
    f32x4 accg[4][2], accu[4][2];
#pragma unroll
    for (int a = 0; a < 4; a++)
#pragma unroll
        for (int b = 0; b < 2; b++) { accg[a][b] = zero; accu[a][b] = zero; }
    int r16 = lane & 15, kq = lane >> 4;
    float4 ra[2], rg[4], ru[4];
#pragma unroll
    for (int i = 0; i < 2; i++) ra[i] = *(const float4*)(ap[i]);
#pragma unroll
    for (int i = 0; i < 4; i++) { rg[i] = *(const float4*)(gp[i]); ru[i] = *(const float4*)(up[i]); }
    for (int k0 = 0; k0 < H_DIM; k0 += 32) {
#pragma unroll
        for (int i = 0; i < 2; i++) *(uint2*)&lA[sa[i]] = pack4(ra[i]);
#pragma unroll
        for (int i = 0; i < 4; i++) { *(uint2*)&lG[sg[i]] = pack4(rg[i]); *(uint2*)&lU[sg[i]] = pack4(ru[i]); }
        __syncthreads();
        if (k0 + 32 < H_DIM) {
            int kn = k0 + 32;
#pragma unroll
            for (int i = 0; i < 2; i++) ra[i] = *(const float4*)(ap[i] + kn);
#pragma unroll
            for (int i = 0; i < 4; i++) { rg[i] = *(const float4*)(gp[i] + kn); ru[i] = *(const float4*)(up[i] + kn); }
        }
        bf16x8 af[4], gf[2], uf[2];
#pragma unroll
        for (int mi = 0; mi < 4; mi++) af[mi] = *(const bf16x8*)&lA[(mi * 16 + r16) * LS + kq * 8];
#pragma unroll
        for (int ni = 0; ni < 2; ni++) {
            gf[ni] = *(const bf16x8*)&lG[(w * 32 + ni * 16 + r16) * LS + kq * 8];
            uf[ni] = *(const bf16x8*)&lU[(w * 32 + ni * 16 + r16) * LS + kq * 8];
        }
#pragma unroll
        for (int mi = 0; mi < 4; mi++)
#pragma unroll
            for (int ni = 0; ni < 2; ni++) {
                accg[mi][ni] = __builtin_amdgcn_mfma_f32_16x16x32_bf16(af[mi], gf[ni], accg[mi][ni], 0, 0, 0);
                accu[mi][ni] = __builtin_amdgcn_mfma_f32_16x16x32_bf16(af[mi], uf[ni], accu[mi][ni], 0, 0, 0);
            }
        __syncthreads();
    }
#pragma unroll
    for (int mi = 0; mi < 4; mi++) {
#pragma unroll
        for (int r = 0; r < 4; r++) {
            int row = mi * 16 + kq * 4 + r;
            int gr = m0 + row;
            if (gr < cnt) {
                float wt = routed ? tw[e * T_TOK + gr] : 1.0f;
                u16* hrow = hout + (size_t)(hbase + gr) * I_DIM + n0 + w * 32;
#pragma unroll
                for (int ni = 0; ni < 2; ni++) {
                    float g = accg[mi][ni][r], u = accu[mi][ni][r];
                    hrow[ni * 16 + r16] = f2bf((g / (1.f + __expf(-g))) * u * wt);
                }
            }
        }
    }
}

__global__ __launch_bounds__(256, 2)
void down_f32(const u16* __restrict__ h_r, const u16* __restrict__ h_s,
              const float* __restrict__ edw, const float* __restrict__ sdw,
              const int* __restrict__ counts, const int* __restrict__ tok,
              float* __restrict__ out) {
    __shared__ u16 lA[64 * LS];
    __shared__ u16 lB[128 * LS];
    int e = blockIdx.z;
    bool routed = (e < NEXP);
    int cnt, hbase; const float* Wd; const u16* hin;
    if (routed) {
        cnt = counts[e];
        int p = 0;
#pragma unroll
        for (int i = 0; i < NEXP; i++) { int c = counts[i]; if (i < e) p += c; }
        hbase = p;
        Wd = edw + (size_t)e * H_DIM * I_DIM; hin = h_r;
    } else { cnt = T_TOK; hbase = 0; Wd = sdw; hin = h_s; }
    int m0 = blockIdx.y * 64;
    if (m0 >= cnt) return;
    int n0 = blockIdx.x * 128;
    int tid = threadIdx.x, lane = tid & 63, w = tid >> 6;
    int arow = tid >> 2, ac8 = tid & 3;
    int hr = m0 + arow; if (hr > cnt - 1) hr = cnt - 1;
    const u16* ap = hin + (size_t)(hbase + hr) * I_DIM + ac8 * 8;
    int sa = arow * LS + ac8 * 8;
    const float* bp[4]; int sb[4];
#pragma unroll
    for (int i = 0; i < 4; i++) {
        int slot = tid + i * 256;
        int row = slot >> 3, c4 = slot & 7;
        bp[i] = Wd + (size_t)(n0 + row) * I_DIM + c4 * 4;
        sb[i] = row * LS + c4 * 4;
    }
    f32x4 zero = {0.f, 0.f, 0.f, 0.f};
    f32x4 acc[4][2];
#pragma unroll
    for (int a = 0; a < 4; a++)
#pragma unroll
        for (int b = 0; b < 2; b++) acc[a][b] = zero;
    int r16 = lane & 15, kq = lane >> 4;
    uint4 ra = *(const uint4*)(ap);
    float4 rb[4];
#pragma unroll
    for (int i = 0; i < 4; i++) rb[i] = *(const float4*)(bp[i]);
    for (int k0 = 0; k0 < I_DIM; k0 += 32) {
        *(uint4*)&lA[sa] = ra;
#pragma unroll
        for (int i = 0; i < 4; i++) *(uint2*)&lB[sb[i]] = pack4(rb[i]);
        __syncthreads();
        if (k0 + 32 < I_DIM) {
            int kn = k0 + 32;
            ra = *(const uint4*)(ap + kn);
#pragma unroll
            for (int i = 0; i < 4; i++) rb[i] = *(const float4*)(bp[i] + kn);
        }
        bf16x8 af[4], bfr[2];
#pragma unroll
        for (int mi = 0; mi < 4; mi++) af[mi] = *(const bf16x8*)&lA[(mi * 16 + r16) * LS + kq * 8];
#pragma unroll
        for (int ni = 0; ni < 2; ni++) bfr[ni] = *(const bf16x8*)&lB[(w * 32 + ni * 16 + r16) * LS + kq * 8];
#pragma unroll
        for (int mi = 0; mi < 4; mi++)
#pragma unroll
            for (int ni = 0; ni < 2; ni++)
                acc[mi][ni] = __builtin_amdgcn_mfma_f32_16x16x32_bf16(af[mi], bfr[ni], acc[mi][ni], 0, 0, 0);
        __syncthreads();
    }
#pragma unroll
    for (int mi = 0; mi < 4; mi++) {
#pragma unroll
        for (int r = 0; r < 4; r++) {
            int row = mi * 16 + kq * 4 + r;
            int gr = m0 + row;
            if (gr < cnt) {
                int t = routed ? tok[e * T_TOK + gr] : gr;
                float* orow = out + (size_t)t * H_DIM + n0 + w * 32;
#pragma unroll
                for (int ni = 0; ni < 2; ni++)
                    atomicAdd(&orow[ni * 16 + r16], acc[mi][ni][r]);
            }
        }
    }
}

extern "C" void kernel_launch(void* const* d_in, const int* in_sizes, int n_in,
                              void* d_out, int out_size, void* d_ws, size_t ws_size,
                              hipStream_t stream) {
    const float* x   = (const float*)d_in[0];
    const float* gw  = (const float*)d_in[1];
    const float* egw = (const float*)d_in[2];
    const float* euw = (const float*)d_in[3];
    const float* edw = (const float*)d_in[4];
    const float* sgw = (const float*)d_in[5];
    const float* suw = (const float*)d_in[6];
    const float* sdw = (const float*)d_in[7];
    float* out = (float*)d_out;

    char* ws = (char*)d_ws;
    int*      counts = (int*)ws;                  // 32 B
    int*      tok    = (int*)(ws + 256);          // 32 KB
    float*    tw     = (float*)(ws + 33024);      // 32 KB
    unsigned* tslot  = (unsigned*)(ws + 65792);   // 8 KB
    u16*      h_r    = (u16*)(ws + 73984);        // 5767168 B
    u16*      h_s    = (u16*)(ws + 5841152);      // 2883584 B
    u16*      xb     = (u16*)(ws + 8724736);      // 4194304 B
    u16*      egb    = (u16*)(ws + 12919040);     // 46137344 B
    u16*      eub    = (u16*)(ws + 59056384);     // 46137344 B
    u16*      edb    = (u16*)(ws + 105193728);    // 46137344 B
    u16*      sgb    = (u16*)(ws + 151331072);    // 5767168 B
    u16*      sub    = (u16*)(ws + 157098240);    // 5767168 B
    u16*      sdb    = (u16*)(ws + 162865408);    // 5767168 B -> end 168632576
    // y buffers overlay egb/eub region (dead after gate_up_bf)
    float*    y_r    = (float*)(ws + 12919040);   // 16777216 B
    float*    y_s    = (float*)(ws + 29696256);   // 8388608 B (ends 38084864 < eub start+... within dead region)

    hipMemsetAsync(counts, 0, 32, stream);

    const size_t NEED = 168632576ull;
    if (ws_size >= NEED) {
        PrepArgs pa;
        pa.cin[0] = egw; pa.cout[0] = egb; pa.n16[0] = 1441792;
        pa.cin[1] = euw; pa.cout[1] = eub; pa.n16[1] = 1441792;
        pa.cin[2] = edw; pa.cout[2] = edb; pa.n16[2] = 1441792;
        pa.cin[3] = sgw; pa.cout[3] = sgb; pa.n16[3] = 180224;
        pa.cin[4] = suw; pa.cout[4] = sub; pa.n16[4] = 180224;
        pa.cin[5] = sdw; pa.cout[5] = sdb; pa.n16[5] = 180224;
        pa.x = x; pa.gw = gw; pa.xb = xb;
        pa.counts = counts; pa.tok = tok; pa.tw = tw; pa.tslot = tslot;
        prep_kernel<<<dim3(1024, 1, 7), 256, 0, stream>>>(pa);
        gate_up_bf<<<dim3(11, 16, 9), 128, 0, stream>>>(xb, egb, eub, sgb, sub, counts, tok, tw, h_r, h_s);
        down_bf<<<dim3(16, 16, 9), 128, 0, stream>>>(h_r, h_s, edb, sdb, counts, tok, y_r, y_s);
        reduce_kernel<<<1024, 256, 0, stream>>>(counts, tslot, y_r, y_s, out);
    } else {
        hipMemsetAsync(out, 0, (size_t)T_TOK * H_DIM * sizeof(float), stream);
        router_kernel<<<256, 256, 0, stream>>>(x, gw, counts, tok, tw);
        gate_up_f32<<<dim3(11, 16, 9), 256, 0, stream>>>(x, egw, euw, sgw, suw, counts, tok, tw, h_r, h_s);
        down_f32<<<dim3(16, 16, 9), 256, 0, stream>>>(h_r, h_s, edw, sdw, counts, tok, out);
    }
}

// Round 5
// 476.628 us; speedup vs baseline: 1.4076x; 1.0573x over previous
//
#include <hip/hip_runtime.h>
#include <hip/hip_bf16.h>

typedef unsigned short u16;
typedef __bf16 bf16x8 __attribute__((ext_vector_type(8)));
typedef float f32x4 __attribute__((ext_vector_type(4)));

#define H_DIM 2048
#define I_DIM 1408
#define T_TOK 1024
#define NEXP 8
#define LS 40  // fallback-path LDS stride

__device__ __forceinline__ u16 f2bf(float f) {
    union { float f; unsigned u; } v; v.f = f;
    unsigned r = v.u + 0x7FFFu + ((v.u >> 16) & 1u);  // RNE
    return (u16)(r >> 16);
}
__device__ __forceinline__ unsigned pack2(float a, float b) {
    float2 t; t.x = a; t.y = b;
    __hip_bfloat162 h = __float22bfloat162_rn(t);  // v_cvt_pk_bf16_f32
    union { __hip_bfloat162 h; unsigned u; } v; v.h = h;
    return v.u;
}
__device__ __forceinline__ uint2 pack4(float4 f) {
    uint2 r; r.x = pack2(f.x, f.y); r.y = pack2(f.z, f.w); return r;
}
__device__ __forceinline__ void g2l16(const void* g, void* l) {
    __builtin_amdgcn_global_load_lds((const __attribute__((address_space(1))) void*)g,
                                     (__attribute__((address_space(3))) void*)l, 16, 0, 0);
}

// ============ prep1: convert gate/up weights (lane-contiguous) + router/x-convert ============
// blocks 0..1583: weight convert (egw 704, euw 704, sgw 88, suw 88; 8192 float4 per block)
// blocks 1584..1839: router (4 tokens/block)
struct Prep1Args {
    const float* src[4]; u16* dst[4];
    const float* x; const float* gw; u16* xb;
    int* counts; int* tok; float* tw; unsigned* tslot;
};

__global__ __launch_bounds__(256)
void prep1_kernel(Prep1Args a) {
    int b = blockIdx.x;
    if (b < 1584) {
        int r, rb;
        if (b < 704)       { r = 0; rb = b; }
        else if (b < 1408) { r = 1; rb = b - 704; }
        else if (b < 1496) { r = 2; rb = b - 1408; }
        else               { r = 3; rb = b - 1496; }
        const float4* in = (const float4*)a.src[r];
        uint2* out = (uint2*)a.dst[r];
        size_t base = (size_t)rb * 8192 + threadIdx.x;
#pragma unroll
        for (int it = 0; it < 4; it++) {
            float4 v[8];
#pragma unroll
            for (int j = 0; j < 8; j++) v[j] = in[base + it * 2048 + j * 256];
#pragma unroll
            for (int j = 0; j < 8; j++) out[base + it * 2048 + j * 256] = pack4(v[j]);
        }
    } else {
        int wave = threadIdx.x >> 6, lane = threadIdx.x & 63;
        int t = (b - 1584) * 4 + wave;
        const float4* xr = (const float4*)(a.x + (size_t)t * H_DIM);
        const float4* gw4 = (const float4*)a.gw;
        uint2* xbr = (uint2*)(a.xb + (size_t)t * H_DIM);
        float acc[NEXP];
#pragma unroll
        for (int e = 0; e < NEXP; e++) acc[e] = 0.f;
#pragma unroll
        for (int j = 0; j < 8; j++) {
            int c = lane + j * 64;
            float4 xv = xr[c];
            xbr[c] = pack4(xv);
#pragma unroll
            for (int e = 0; e < NEXP; e++) {
                float4 gv = gw4[e * 512 + c];
                acc[e] += xv.x * gv.x + xv.y * gv.y + xv.z * gv.z + xv.w * gv.w;
            }
        }
#pragma unroll
        for (int e = 0; e < NEXP; e++) {
#pragma unroll
            for (int off = 32; off > 0; off >>= 1) acc[e] += __shfl_xor(acc[e], off);
        }
        if (lane == 0) {
            int i0 = 0; float v0 = acc[0];
#pragma unroll
            for (int e = 1; e < NEXP; e++) if (acc[e] > v0) { v0 = acc[e]; i0 = e; }
            int i1 = -1; float v1 = -3.0e38f;
#pragma unroll
            for (int e = 0; e < NEXP; e++) if (e != i0 && acc[e] > v1) { v1 = acc[e]; i1 = e; }
            float ex = __expf(v1 - v0);
            float w0 = 1.f / (1.f + ex);
            float w1 = 1.f - w0;
            int s0 = atomicAdd(&a.counts[i0], 1);
            a.tok[i0 * T_TOK + s0] = t; a.tw[i0 * T_TOK + s0] = w0;
            a.tslot[t * 2] = ((unsigned)i0 << 16) | (unsigned)s0;
            int s1 = atomicAdd(&a.counts[i1], 1);
            a.tok[i1 * T_TOK + s1] = t; a.tw[i1 * T_TOK + s1] = w1;
            a.tslot[t * 2 + 1] = ((unsigned)i1 << 16) | (unsigned)s1;
        }
    }
}

// ============ gate+up GEMM (z<9) + down-weight convert (z==9) ============
// GEMM: 256 threads / 4 waves; block 64Mx128N; wave 64Mx32N; BK=64; XOR-swizzled LDS.
#define EDW_F4 5767168
__global__ __launch_bounds__(256, 3)
void gate_up_bf(const u16* __restrict__ xb,
                const u16* __restrict__ egb, const u16* __restrict__ eub,
                const u16* __restrict__ sgb, const u16* __restrict__ sub,
                const int* __restrict__ counts, const int* __restrict__ tok,
                const float* __restrict__ tw,
                u16* __restrict__ h_r, u16* __restrict__ h_s,
                const float* __restrict__ edw_f, const float* __restrict__ sdw_f,
                u16* __restrict__ edb, u16* __restrict__ sdb) {
    int e = blockIdx.z;
    if (e == 9) {  // convert edw/sdw -> bf16, overlapped with the GEMM blocks
        int b = blockIdx.y * 11 + blockIdx.x;           // 0..175
        size_t base = (size_t)b * 36864 + threadIdx.x;  // 176*36864 = 6488064 f4 exact
        const float4* ein = (const float4*)edw_f;
        const float4* sin_ = (const float4*)sdw_f;
        uint2* eout = (uint2*)edb;
        uint2* sout = (uint2*)sdb;
        for (int it = 0; it < 18; it++) {
            size_t g0 = base + (size_t)it * 2048;
            float4 v[8];
#pragma unroll
            for (int j = 0; j < 8; j++) {
                size_t g = g0 + j * 256;
                v[j] = (g < EDW_F4) ? ein[g] : sin_[g - EDW_F4];
            }
#pragma unroll
            for (int j = 0; j < 8; j++) {
                size_t g = g0 + j * 256;
                if (g < EDW_F4) eout[g] = pack4(v[j]);
                else            sout[g - EDW_F4] = pack4(v[j]);
            }
        }
        return;
    }

    __shared__ u16 lA[64 * 64];    // 8 KB
    __shared__ u16 lG[128 * 64];   // 16 KB
    __shared__ u16 lU[128 * 64];   // 16 KB

    bool routed = (e < NEXP);
    int cnt, hbase; const u16 *Wg, *Wu; u16* hout;
    if (routed) {
        cnt = counts[e];
        int p = 0;
#pragma unroll
        for (int i = 0; i < NEXP; i++) { int c = counts[i]; if (i < e) p += c; }
        hbase = p;
        Wg = egb + (size_t)e * I_DIM * H_DIM;
        Wu = eub + (size_t)e * I_DIM * H_DIM;
        hout = h_r;
    } else { cnt = T_TOK; hbase = 0; Wg = sgb; Wu = sub; hout = h_s; }
    int m0 = blockIdx.y * 64;
    if (m0 >= cnt) return;
    int n0 = blockIdx.x * 128;

    int tid = threadIdx.x, lane = tid & 63, w = tid >> 6;

    // A: 512 chunks (64 rows x 8); wave w instr j<2 covers chunks [w*128+j*64, +64)
    const u16* aptr[2]; u16* alds[2];
#pragma unroll
    for (int j = 0; j < 2; j++) {
        int chunk = w * 128 + j * 64 + lane;
        int row = chunk >> 3, cl = chunk & 7;
        int cg = cl ^ (row & 7);
        int trow = m0 + row; if (trow > cnt - 1) trow = cnt - 1;
        int tix = routed ? tok[e * T_TOK + trow] : trow;
        aptr[j] = xb + (size_t)tix * H_DIM + cg * 8;
        alds[j] = &lA[(w * 128 + j * 64) * 8];
    }
    // G/U: 1024 chunks each; wave w instr j<4 covers [w*256+j*64, +64)
    const u16* gptr[4]; const u16* uptr[4]; u16* glds[4]; u16* ulds[4];
#pragma unroll
    for (int j = 0; j < 4; j++) {
        int chunk = w * 256 + j * 64 + lane;
        int row = chunk >> 3, cl = chunk & 7;
        int cg = cl ^ (row & 7);
        gptr[j] = Wg + (size_t)(n0 + row) * H_DIM + cg * 8;
        uptr[j] = Wu + (size_t)(n0 + row) * H_DIM + cg * 8;
        glds[j] = &lG[(w * 256 + j * 64) * 8];
        ulds[j] = &lU[(w * 256 + j * 64) * 8];
    }

    f32x4 zero = {0.f, 0.f, 0.f, 0.f};
    f32x4 accg[4][2], accu[4][2];
#pragma unroll
    for (int a = 0; a < 4; a++)
#pragma unroll
        for (int b = 0; b < 2; b++) { accg[a][b] = zero; accu[a][b] = zero; }

    int r16 = lane & 15, q = lane >> 4;

    for (int k0 = 0; k0 < H_DIM; k0 += 64) {
#pragma unroll
        for (int j = 0; j < 2; j++) g2l16(aptr[j] + k0, alds[j]);
#pragma unroll
        for (int j = 0; j < 4; j++) { g2l16(gptr[j] + k0, glds[j]); g2l16(uptr[j] + k0, ulds[j]); }
        __syncthreads();
#pragma unroll
        for (int kh = 0; kh < 2; kh++) {
            bf16x8 af[4], gf[2], uf[2];
#pragma unroll
            for (int mi = 0; mi < 4; mi++) {
                int row = mi * 16 + r16;
                int ch = (kh * 4 + q) ^ (row & 7);
                af[mi] = *(const bf16x8*)&lA[row * 64 + ch * 8];
            }
#pragma unroll
            for (int ni = 0; ni < 2; ni++) {
                int row = w * 32 + ni * 16 + r16;
                int ch = (kh * 4 + q) ^ (row & 7);
                gf[ni] = *(const bf16x8*)&lG[row * 64 + ch * 8];
                uf[ni] = *(const bf16x8*)&lU[row * 64 + ch * 8];
            }
#pragma unroll
            for (int mi = 0; mi < 4; mi++)
#pragma unroll
                for (int ni = 0; ni < 2; ni++) {
                    accg[mi][ni] = __builtin_amdgcn_mfma_f32_16x16x32_bf16(af[mi], gf[ni], accg[mi][ni], 0, 0, 0);
                    accu[mi][ni] = __builtin_amdgcn_mfma_f32_16x16x32_bf16(af[mi], uf[ni], accu[mi][ni], 0, 0, 0);
                }
        }
        __syncthreads();
    }

    // epilogue: C/D col=lane&15, row=(lane>>4)*4+reg
#pragma unroll
    for (int mi = 0; mi < 4; mi++) {
#pragma unroll
        for (int r = 0; r < 4; r++) {
            int row = mi * 16 + q * 4 + r;
            int gr = m0 + row;
            if (gr < cnt) {
                float wt = routed ? tw[e * T_TOK + gr] : 1.0f;
                u16* hrow = hout + (size_t)(hbase + gr) * I_DIM + n0 + w * 32;
#pragma unroll
                for (int ni = 0; ni < 2; ni++) {
                    float g = accg[mi][ni][r], u = accu[mi][ni][r];
                    hrow[ni * 16 + r16] = f2bf((g / (1.f + __expf(-g))) * u * wt);
                }
            }
        }
    }
}

// ============ down GEMM: 256 threads, 64Mx128N, wave 64x32, BK=64; fp32 stores to y ============
__global__ __launch_bounds__(256, 3)
void down_bf(const u16* __restrict__ h_r, const u16* __restrict__ h_s,
             const u16* __restrict__ edb, const u16* __restrict__ sdb,
             const int* __restrict__ counts, const int* __restrict__ tok,
             float* __restrict__ y_r, float* __restrict__ y_s) {
    __shared__ u16 lA[64 * 64];    // 8 KB
    __shared__ u16 lB[128 * 64];   // 16 KB

    int e = blockIdx.z;
    bool routed = (e < NEXP);
    int cnt, hbase; const u16* Wd; const u16* hin;
    if (routed) {
        cnt = counts[e];
        int p = 0;
#pragma unroll
        for (int i = 0; i < NEXP; i++) { int c = counts[i]; if (i < e) p += c; }
        hbase = p;
        Wd = edb + (size_t)e * H_DIM * I_DIM;
        hin = h_r;
    } else { cnt = T_TOK; hbase = 0; Wd = sdb; hin = h_s; }
    int m0 = blockIdx.y * 64;
    if (m0 >= cnt) return;
    int n0 = blockIdx.x * 128;

    int tid = threadIdx.x, lane = tid & 63, w = tid >> 6;

    const u16* aptr[2]; u16* alds[2];
#pragma unroll
    for (int j = 0; j < 2; j++) {
        int chunk = w * 128 + j * 64 + lane;
        int row = chunk >> 3, cl = chunk & 7;
        int cg = cl ^ (row & 7);
        int hr = m0 + row; if (hr > cnt - 1) hr = cnt - 1;
        aptr[j] = hin + (size_t)(hbase + hr) * I_DIM + cg * 8;
        alds[j] = &lA[(w * 128 + j * 64) * 8];
    }
    const u16* bptr[4]; u16* blds[4];
#pragma unroll
    for (int j = 0; j < 4; j++) {
        int chunk = w * 256 + j * 64 + lane;
        int row = chunk >> 3, cl = chunk & 7;
        int cg = cl ^ (row & 7);
        bptr[j] = Wd + (size_t)(n0 + row) * I_DIM + cg * 8;
        blds[j] = &lB[(w * 256 + j * 64) * 8];
    }

    f32x4 zero = {0.f, 0.f, 0.f, 0.f};
    f32x4 acc[4][2];
#pragma unroll
    for (int a = 0; a < 4; a++)
#pragma unroll
        for (int b = 0; b < 2; b++) acc[a][b] = zero;

    int r16 = lane & 15, q = lane >> 4;

    for (int k0 = 0; k0 < I_DIM; k0 += 64) {  // 1408 = 22*64
#pragma unroll
        for (int j = 0; j < 2; j++) g2l16(aptr[j] + k0, alds[j]);
#pragma unroll
        for (int j = 0; j < 4; j++) g2l16(bptr[j] + k0, blds[j]);
        __syncthreads();
#pragma unroll
        for (int kh = 0; kh < 2; kh++) {
            bf16x8 af[4], bfr[2];
#pragma unroll
            for (int mi = 0; mi < 4; mi++) {
                int row = mi * 16 + r16;
                int ch = (kh * 4 + q) ^ (row & 7);
                af[mi] = *(const bf16x8*)&lA[row * 64 + ch * 8];
            }
#pragma unroll
            for (int ni = 0; ni < 2; ni++) {
                int row = w * 32 + ni * 16 + r16;
                int ch = (kh * 4 + q) ^ (row & 7);
                bfr[ni] = *(const bf16x8*)&lB[row * 64 + ch * 8];
            }
#pragma unroll
            for (int mi = 0; mi < 4; mi++)
#pragma unroll
                for (int ni = 0; ni < 2; ni++)
                    acc[mi][ni] = __builtin_amdgcn_mfma_f32_16x16x32_bf16(af[mi], bfr[ni], acc[mi][ni], 0, 0, 0);
        }
        __syncthreads();
    }

#pragma unroll
    for (int mi = 0; mi < 4; mi++) {
#pragma unroll
        for (int r = 0; r < 4; r++) {
            int row = mi * 16 + q * 4 + r;
            int gr = m0 + row;
            if (gr < cnt) {
                float* yrow = (routed ? y_r + (size_t)(hbase + gr) * H_DIM
                                      : y_s + (size_t)gr * H_DIM) + n0 + w * 32;
#pragma unroll
                for (int ni = 0; ni < 2; ni++)
                    yrow[ni * 16 + r16] = acc[mi][ni][r];
            }
        }
    }
}

// ============ reduce: out[t] = y_s[t] + y_r[slot0(t)] + y_r[slot1(t)] ============
__global__ __launch_bounds__(256)
void reduce_kernel(const int* __restrict__ counts, const unsigned* __restrict__ tslot,
                   const float* __restrict__ y_r, const float* __restrict__ y_s,
                   float* __restrict__ out) {
    int t = blockIdx.x;
    int pre[NEXP]; int run = 0;
#pragma unroll
    for (int i = 0; i < NEXP; i++) { pre[i] = run; run += counts[i]; }
    unsigned t0 = tslot[t * 2], t1 = tslot[t * 2 + 1];
    int r0 = pre[t0 >> 16] + (int)(t0 & 0xffffu);
    int r1 = pre[t1 >> 16] + (int)(t1 & 0xffffu);
    const float4* ys = (const float4*)(y_s + (size_t)t * H_DIM);
    const float4* a0 = (const float4*)(y_r + (size_t)r0 * H_DIM);
    const float4* a1 = (const float4*)(y_r + (size_t)r1 * H_DIM);
    float4* o = (float4*)(out + (size_t)t * H_DIM);
#pragma unroll
    for (int j = 0; j < 2; j++) {
        int c = threadIdx.x + j * 256;  // 512 float4 per row
        float4 s = ys[c], b0 = a0[c], b1 = a1[c];
        float4 r;
        r.x = s.x + b0.x + b1.x; r.y = s.y + b0.y + b1.y;
        r.z = s.z + b0.z + b1.z; r.w = s.w + b0.w + b1.w;
        o[c] = r;
    }
}

// ================= FALLBACK PATH (fp32, only if ws too small) =================
__global__ __launch_bounds__(256)
void router_kernel(const float* __restrict__ x, const float* __restrict__ gw,
                   int* __restrict__ counts, int* __restrict__ tok, float* __restrict__ tw) {
    int wave = threadIdx.x >> 6;
    int lane = threadIdx.x & 63;
    int t = blockIdx.x * 4 + wave;
    const float* xr = x + (size_t)t * H_DIM;
    float acc[NEXP];
#pragma unroll
    for (int e = 0; e < NEXP; e++) acc[e] = 0.f;
    for (int h = lane; h < H_DIM; h += 64) {
        float xv = xr[h];
#pragma unroll
        for (int e = 0; e < NEXP; e++) acc[e] += xv * gw[e * H_DIM + h];
    }
#pragma unroll
    for (int e = 0; e < NEXP; e++) {
#pragma unroll
        for (int off = 32; off > 0; off >>= 1) acc[e] += __shfl_xor(acc[e], off);
    }
    if (lane == 0) {
        int i0 = 0; float v0 = acc[0];
#pragma unroll
        for (int e = 1; e < NEXP; e++) if (acc[e] > v0) { v0 = acc[e]; i0 = e; }
        int i1 = -1; float v1 = -3.0e38f;
#pragma unroll
        for (int e = 0; e < NEXP; e++) if (e != i0 && acc[e] > v1) { v1 = acc[e]; i1 = e; }
        float ex = __expf(v1 - v0);
        float w0 = 1.f / (1.f + ex);
        float w1 = 1.f - w0;
        int s0 = atomicAdd(&counts[i0], 1);
        tok[i0 * T_TOK + s0] = t; tw[i0 * T_TOK + s0] = w0;
        int s1 = atomicAdd(&counts[i1], 1);
        tok[i1 * T_TOK + s1] = t; tw[i1 * T_TOK + s1] = w1;
    }
}

__global__ __launch_bounds__(256, 2)
void gate_up_f32(const float* __restrict__ x,
                 const float* __restrict__ egw, const float* __restrict__ euw,
                 const float* __restrict__ sgw, const float* __restrict__ suw,
                 const int* __restrict__ counts, const int* __restrict__ tok,
                 const float* __restrict__ tw,
                 u16* __restrict__ h_r, u16* __restrict__ h_s) {
    __shared__ u16 lA[64 * LS];
    __shared__ u16 lG[128 * LS];
    __shared__ u16 lU[128 * LS];
    int e = blockIdx.z;
    bool routed = (e < NEXP);
    int cnt, hbase; const float *Wg, *Wu; u16* hout;
    if (routed) {
        cnt = counts[e];
        int p = 0;
#pragma unroll
        for (int i = 0; i < NEXP; i++) { int c = counts[i]; if (i < e) p += c; }
        hbase = p;
        Wg = egw + (size_t)e * I_DIM * H_DIM; Wu = euw + (size_t)e * I_DIM * H_DIM; hout = h_r;
    } else { cnt = T_TOK; hbase = 0; Wg = sgw; Wu = suw; hout = h_s; }
    int m0 = blockIdx.y * 64;
    if (m0 >= cnt) return;
    int n0 = blockIdx.x * 128;
    int tid = threadIdx.x, lane = tid & 63, w = tid >> 6;
    const float* ap[2]; int sa[2];
#pragma unroll
    for (int i = 0; i < 2; i++) {
        int slot = tid + i * 256;
        int row = slot >> 3, c4 = slot & 7;
        sa[i] = row * LS + c4 * 4;
        int trow = m0 + row; if (trow > cnt - 1) trow = cnt - 1;
        int tix = routed ? tok[e * T_TOK + trow] : trow;
        ap[i] = x + (size_t)tix * H_DIM + c4 * 4;
    }
    const float* gp[4]; const float* up[4]; int sg[4];
#pragma unroll
    for (int i = 0; i < 4; i++) {
        int slot = tid + i * 256;
        int row = slot >> 3, c4 = slot & 7;
        sg[i] = row * LS + c4 * 4;
        gp[i] = Wg + (size_t)(n0 + row) * H_DIM + c4 * 4;
        up[i] = Wu + (size_t)(n0 + row) * H_DIM + c4 * 4;
    }
    f32x4 zero = {0.f, 0.f, 0.f, 0.f};
    f32x4 accg[4][2], accu[4][2];
#pragma unroll
    for (int a = 0; a < 4; a++)
#pragma unroll
        for (int b = 0; b < 2; b++) { accg[a][b] = zero; accu[a][b] = zero; }
    int r16 = lane & 15, kq = lane >> 4;
    float4 ra[2], rg[4], ru[4];
#pragma unroll
    for (int i = 0; i < 2; i++) ra[i] = *(const float4*)(ap[i]);
#pragma unroll
    for (int i = 0; i < 4; i++) { rg[i] = *(const float4*)(gp[i]); ru[i] = *(const float4*)(up[i]); }
    for (int k0 = 0; k0 < H_DIM; k0 += 32) {
#pragma unroll
        for (int i = 0; i < 2; i++) *(uint2*)&lA[sa[i]] = pack4(ra[i]);
#pragma unroll
        for (int i = 0; i < 4; i++) { *(uint2*)&lG[sg[i]] = pack4(rg[i]); *(uint2*)&lU[sg[i]] = pack4(ru[i]); }
        __syncthreads();
        if (k0 + 32 < H_DIM) {
            int kn = k0 + 32;
#pragma unroll
            for (int i = 0; i < 2; i++) ra[i] = *(const float4*)(ap[i] + kn);
#pragma unroll
            for (int i = 0; i < 4; i++) { rg[i] = *(const float4*)(gp[i] + kn); ru[i] = *(const float4*)(up[i] + kn); }
        }
        bf16x8 af[4], gf[2], uf[2];
#pragma unroll
        for (int mi = 0; mi < 4; mi++) af[mi] = *(const bf16x8*)&lA[(mi * 16 + r16) * LS + kq * 8];
#pragma unroll
        for (int ni = 0; ni < 2; ni++) {
            gf[ni] = *(const bf16x8*)&lG[(w * 32 + ni * 16 + r16) * LS + kq * 8];
            uf[ni] = *(const bf16x8*)&lU[(w * 32 + ni * 16 + r16) * LS + kq * 8];
        }
#pragma unroll
        for (int mi = 0; mi < 4; mi++)
#pragma unroll
            for (int ni = 0; ni < 2; ni++) {
                accg[mi][ni] = __builtin_amdgcn_mfma_f32_16x16x32_bf16(af[mi], gf[ni], accg[mi][ni], 0, 0, 0);
                accu[mi][ni] = __builtin_amdgcn_mfma_f32_16x16x32_bf16(af[mi], uf[ni], accu[mi][ni], 0, 0, 0);
            }
        __syncthreads();
    }
#pragma unroll
    for (int mi = 0; mi < 4; mi++) {
#pragma unroll
        for (int r = 0; r < 4; r++) {
            int row = mi * 16 + kq * 4 + r;
            int gr = m0 + row;
            if (gr < cnt) {
                float wt = routed ? tw[e * T_TOK + gr] : 1.0f;
                u16* hrow = hout + (size_t)(hbase + gr) * I_DIM + n0 + w * 32;
#pragma unroll
                for (int ni = 0; ni < 2; ni++) {
                    float g = accg[mi][ni][r], u = accu[mi][ni][r];
                    hrow[ni * 16 + r16] = f2bf((g / (1.f + __expf(-g))) * u * wt);
                }
            }
        }
    }
}

__global__ __launch_bounds__(256, 2)
void down_f32(const u16* __restrict__ h_r, const u16* __restrict__ h_s,
              const float* __restrict__ edw, const float* __restrict__ sdw,
              const int* __restrict__ counts, const int* __restrict__ tok,
              float* __restrict__ out) {
    __shared__ u16 lA[64 * LS];
    __shared__ u16 lB[128 * LS];
    int e = blockIdx.z;
    bool routed = (e < NEXP);
    int cnt, hbase; const float* Wd; const u16* hin;
    if (routed) {
        cnt = counts[e];
        int p = 0;
#pragma unroll
        for (int i = 0; i < NEXP; i++) { int c = counts[i]; if (i < e) p += c; }
        hbase = p;
        Wd = edw + (size_t)e * H_DIM * I_DIM; hin = h_r;
    } else { cnt = T_TOK; hbase = 0; Wd = sdw; hin = h_s; }
    int m0 = blockIdx.y * 64;
    if (m0 >= cnt) return;
    int n0 = blockIdx.x * 128;
    int tid = threadIdx.x, lane = tid & 63, w = tid >> 6;
    int arow = tid >> 2, ac8 = tid & 3;
    int hr = m0 + arow; if (hr > cnt - 1) hr = cnt - 1;
    const u16* ap = hin + (size_t)(hbase + hr) * I_DIM + ac8 * 8;
    int sa = arow * LS + ac8 * 8;
    const float* bp[4]; int sb[4];
#pragma unroll
    for (int i = 0; i < 4; i++) {
        int slot = tid + i * 256;
        int row = slot >> 3, c4 = slot & 7;
        bp[i] = Wd + (size_t)(n0 + row) * I_DIM + c4 * 4;
        sb[i] = row * LS + c4 * 4;
    }
    f32x4 zero = {0.f, 0.f, 0.f, 0.f};
    f32x4 acc[4][2];
#pragma unroll
    for (int a = 0; a < 4; a++)
#pragma unroll
        for (int b = 0; b < 2; b++) acc[a][b] = zero;
    int r16 = lane & 15, kq = lane >> 4;
    uint4 ra = *(const uint4*)(ap);
    float4 rb[4];
#pragma unroll
    for (int i = 0; i < 4; i++) rb[i] = *(const float4*)(bp[i]);
    for (int k0 = 0; k0 < I_DIM; k0 += 32) {
        *(uint4*)&lA[sa] = ra;
#pragma unroll
        for (int i = 0; i < 4; i++) *(uint2*)&lB[sb[i]] = pack4(rb[i]);
        __syncthreads();
        if (k0 + 32 < I_DIM) {
            int kn = k0 + 32;
            ra = *(const uint4*)(ap + kn);
#pragma unroll
            for (int i = 0; i < 4; i++) rb[i] = *(const float4*)(bp[i] + kn);
        }
        bf16x8 af[4], bfr[2];
#pragma unroll
        for (int mi = 0; mi < 4; mi++) af[mi] = *(const bf16x8*)&lA[(mi * 16 + r16) * LS + kq * 8];
#pragma unroll
        for (int ni = 0; ni < 2; ni++) bfr[ni] = *(const bf16x8*)&lB[(w * 32 + ni * 16 + r16) * LS + kq * 8];
#pragma unroll
        for (int mi = 0; mi < 4; mi++)
#pragma unroll
            for (int ni = 0; ni < 2; ni++)
                acc[mi][ni] = __builtin_amdgcn_mfma_f32_16x16x32_bf16(af[mi], bfr[ni], acc[mi][ni], 0, 0, 0);
        __syncthreads();
    }
#pragma unroll
    for (int mi = 0; mi < 4; mi++) {
#pragma unroll
        for (int r = 0; r < 4; r++) {
            int row = mi * 16 + kq * 4 + r;
            int gr = m0 + row;
            if (gr < cnt) {
                int t = routed ? tok[e * T_TOK + gr] : gr;
                float* orow = out + (size_t)t * H_DIM + n0 + w * 32;
#pragma unroll
                for (int ni = 0; ni < 2; ni++)
                    atomicAdd(&orow[ni * 16 + r16], acc[mi][ni][r]);
            }
        }
    }
}

extern "C" void kernel_launch(void* const* d_in, const int* in_sizes, int n_in,
                              void* d_out, int out_size, void* d_ws, size_t ws_size,
                              hipStream_t stream) {
    const float* x   = (const float*)d_in[0];
    const float* gw  = (const float*)d_in[1];
    const float* egw = (const float*)d_in[2];
    const float* euw = (const float*)d_in[3];
    const float* edw = (const float*)d_in[4];
    const float* sgw = (const float*)d_in[5];
    const float* suw = (const float*)d_in[6];
    const float* sdw = (const float*)d_in[7];
    float* out = (float*)d_out;

    char* ws = (char*)d_ws;
    int*      counts = (int*)ws;                  // 32 B
    int*      tok    = (int*)(ws + 256);          // 32 KB
    float*    tw     = (float*)(ws + 33024);      // 32 KB
    unsigned* tslot  = (unsigned*)(ws + 65792);   // 8 KB
    u16*      h_r    = (u16*)(ws + 73984);        // 5767168 B
    u16*      h_s    = (u16*)(ws + 5841152);      // 2883584 B
    u16*      xb     = (u16*)(ws + 8724736);      // 4194304 B
    u16*      egb    = (u16*)(ws + 12919040);     // 46137344 B
    u16*      eub    = (u16*)(ws + 59056384);     // 46137344 B
    u16*      edb    = (u16*)(ws + 105193728);    // 46137344 B
    u16*      sgb    = (u16*)(ws + 151331072);    // 5767168 B
    u16*      sub    = (u16*)(ws + 157098240);    // 5767168 B
    u16*      sdb    = (u16*)(ws + 162865408);    // 5767168 B -> end 168632576
    // y buffers overlay egb/eub (dead after gate_up dispatch)
    float*    y_r    = (float*)(ws + 12919040);   // 16777216 B
    float*    y_s    = (float*)(ws + 29696256);   // 8388608 B

    hipMemsetAsync(counts, 0, 32, stream);

    const size_t NEED = 168632576ull;
    if (ws_size >= NEED) {
        Prep1Args pa;
        pa.src[0] = egw; pa.dst[0] = egb;
        pa.src[1] = euw; pa.dst[1] = eub;
        pa.src[2] = sgw; pa.dst[2] = sgb;
        pa.src[3] = suw; pa.dst[3] = sub;
        pa.x = x; pa.gw = gw; pa.xb = xb;
        pa.counts = counts; pa.tok = tok; pa.tw = tw; pa.tslot = tslot;
        prep1_kernel<<<1840, 256, 0, stream>>>(pa);
        // z 0..7 routed, z==8 shared, z==9 edw/sdw bf16 convert (overlapped)
        gate_up_bf<<<dim3(11, 16, 10), 256, 0, stream>>>(xb, egb, eub, sgb, sub, counts, tok, tw,
                                                         h_r, h_s, edw, sdw, edb, sdb);
        down_bf<<<dim3(16, 16, 9), 256, 0, stream>>>(h_r, h_s, edb, sdb, counts, tok, y_r, y_s);
        reduce_kernel<<<1024, 256, 0, stream>>>(counts, tslot, y_r, y_s, out);
    } else {
        hipMemsetAsync(out, 0, (size_t)T_TOK * H_DIM * sizeof(float), stream);
        router_kernel<<<256, 256, 0, stream>>>(x, gw, counts, tok, tw);
        gate_up_f32<<<dim3(11, 16, 9), 256, 0, stream>>>(x, egw, euw, sgw, suw, counts, tok, tw, h_r, h_s);
        down_f32<<<dim3(16, 16, 9), 256, 0, stream>>>(h_r, h_s, edw, sdw, counts, tok, out);
    }
}